// Round 1
// baseline (525.701 us; speedup 1.0000x reference)
//
// Fused attention block (QKV proj + RoPE + flash attention + out proj), MI355X gfx950.
// Pipeline: cvt fp32->bf16 -> rope tables -> GEMM qkv (bf16 MFMA, m97 structure)
//   -> rope in-place on q,k (scale folded into q) -> V transpose -> flash attn
//   -> GEMM out (fp32 output).
// All GEMM/attn math: bf16 inputs, fp32 MFMA accumulation, fp32 softmax.
// Workspace layout (needs ~113 MiB):
//   [0,16M)    x_bf16, later reused as attn_out
//   [16,40M)   w_qkv bf16
//   [40,48M)   w_out bf16
//   [48,96M)   qkv   bf16 [4096][6144]
//   [96,112M)  v^T   bf16 [32*128][2048]
//   [112M,..)  cos/sin tables fp32 [2048][64] each

#include <hip/hip_runtime.h>
#include <math.h>
#include <stdint.h>

typedef unsigned short u16;
typedef unsigned int u32;
typedef float f32x4 __attribute__((ext_vector_type(4)));
typedef __bf16 bf16x8 __attribute__((ext_vector_type(8)));

typedef const __attribute__((address_space(1))) u32* gas1;
typedef __attribute__((address_space(3))) u32* las3;

#define B_ 2
#define S_ 2048
#define DM_ 2048
#define H_ 16
#define HD_ 128
#define NO_ 6144
#define M_ 4096

__device__ __forceinline__ u16 f2bf(float f) {
  u32 u = __float_as_uint(f);
  u32 r = (u + 0x7fffu + ((u >> 16) & 1u)) >> 16;  // RNE
  return (u16)r;
}
__device__ __forceinline__ float bf2f(u16 h) {
  return __uint_as_float(((u32)h) << 16);
}

// ---------------------------------------------------------------- convert
__global__ void cvt_bf16(const float* __restrict__ in, u16* __restrict__ out, int n) {
  int i = (blockIdx.x * blockDim.x + threadIdx.x) * 4;
  int stride = gridDim.x * blockDim.x * 4;
  for (; i < n; i += stride) {
    float4 v = *(const float4*)(in + i);
    ushort4 o;
    o.x = f2bf(v.x); o.y = f2bf(v.y); o.z = f2bf(v.z); o.w = f2bf(v.w);
    *(ushort4*)(out + i) = o;
  }
}

// ---------------------------------------------------------------- rope tables
__global__ void rope_tables(float* __restrict__ ct, float* __restrict__ st) {
  int i = blockIdx.x * blockDim.x + threadIdx.x;  // S_*64 threads
  int s = i >> 6, j = i & 63;
  float inv = powf(10000.0f, -(float)j / 64.0f);
  float f = (float)s * inv;
  ct[i] = cosf(f);
  st[i] = sinf(f);
}

// ---------------------------------------------------------------- GEMM  C = A * B^T
// A [M][K] bf16 row-major, B [N][K] bf16 row-major (B^T layout), both K%32==0.
// m97 structure: 128x128 tile, BK=32, 256 thr (4 waves, 2x2), 4x4 16x16x32 frags/wave,
// global_load_lds width 16, 2 barriers per K-step.
template <int OUT_BF16>
__global__ __launch_bounds__(256) void gemm_bt(const u16* __restrict__ A,
                                               const u16* __restrict__ B,
                                               void* __restrict__ Cv,
                                               int M, int N, int K) {
  __shared__ u16 lA[128 * 32];
  __shared__ u16 lB[128 * 32];
  const int t = threadIdx.x;
  const int m0 = blockIdx.y * 128, n0 = blockIdx.x * 128;
  const int w = t >> 6, l = t & 63, lr = l & 15, lg = l >> 4;
  const int wm = (w >> 1) * 64, wn = (w & 1) * 64;
  f32x4 acc[4][4] = {};
  const int srow = t >> 2;       // staging row 0..63 (per round)
  const int scol = (t & 3) * 8;  // staging col chunk
  const u16* Ag = A + (size_t)(m0 + srow) * K + scol;
  const u16* Bg = B + (size_t)(n0 + srow) * K + scol;

  for (int k0 = 0; k0 < K; k0 += 32) {
    __syncthreads();  // previous tile fully consumed
#pragma unroll
    for (int i = 0; i < 2; i++) {
      __builtin_amdgcn_global_load_lds((gas1)(Ag + (size_t)i * 64 * K + k0),
                                       (las3)(lA + (i * 256 + w * 64) * 8), 16, 0, 0);
      __builtin_amdgcn_global_load_lds((gas1)(Bg + (size_t)i * 64 * K + k0),
                                       (las3)(lB + (i * 256 + w * 64) * 8), 16, 0, 0);
    }
    __syncthreads();  // staged tile visible
    bf16x8 af[4], bfr[4];
#pragma unroll
    for (int mi = 0; mi < 4; mi++)
      af[mi] = *(const bf16x8*)&lA[(wm + mi * 16 + lr) * 32 + lg * 8];
#pragma unroll
    for (int ni = 0; ni < 4; ni++)
      bfr[ni] = *(const bf16x8*)&lB[(wn + ni * 16 + lr) * 32 + lg * 8];
#pragma unroll
    for (int mi = 0; mi < 4; mi++)
#pragma unroll
      for (int ni = 0; ni < 4; ni++)
        acc[mi][ni] =
            __builtin_amdgcn_mfma_f32_16x16x32_bf16(af[mi], bfr[ni], acc[mi][ni], 0, 0, 0);
  }

  // epilogue: D row=(lane>>4)*4+j, col=lane&15 (m89/m91-verified layout)
#pragma unroll
  for (int mi = 0; mi < 4; mi++)
#pragma unroll
    for (int ni = 0; ni < 4; ni++) {
      int row = m0 + wm + mi * 16 + lg * 4;
      int col = n0 + wn + ni * 16 + lr;
      if (OUT_BF16) {
        u16* C = (u16*)Cv;
#pragma unroll
        for (int j = 0; j < 4; j++) C[(size_t)(row + j) * N + col] = f2bf(acc[mi][ni][j]);
      } else {
        float* C = (float*)Cv;
#pragma unroll
        for (int j = 0; j < 4; j++) C[(size_t)(row + j) * N + col] = acc[mi][ni][j];
      }
    }
}

// ---------------------------------------------------------------- RoPE in place on q,k
// thread -> (row=b*S+s, hh in [0,32): 0-15 q heads, 16-31 k heads, j in [0,64))
// out[j]    = e1*cos - e2*sin ;  out[j+64] = e2*cos + e1*sin ;  q also * 1/sqrt(128)
__global__ void rope_apply(u16* __restrict__ qkv, const float* __restrict__ ct,
                           const float* __restrict__ st) {
  int i = blockIdx.x * blockDim.x + threadIdx.x;  // M_*32*64 threads
  int j = i & 63;
  int hh = (i >> 6) & 31;
  int row = i >> 11;
  int s = row & (S_ - 1);
  int col = (hh < 16) ? hh * 128 : 2048 + (hh - 16) * 128;
  u16* p = qkv + (size_t)row * NO_ + col + j;
  float e1 = bf2f(p[0]), e2 = bf2f(p[64]);
  float c = ct[(s << 6) + j], sn = st[(s << 6) + j];
  float o1 = e1 * c - e2 * sn;
  float o2 = e2 * c + e1 * sn;
  if (hh < 16) {  // fold softmax scale into q (commutes with rotation)
    o1 *= 0.08838834764831845f;
    o2 *= 0.08838834764831845f;
  }
  p[0] = f2bf(o1);
  p[64] = f2bf(o2);
}

// ---------------------------------------------------------------- V transpose
// qkv[b*S+s][4096 + h*128 + d] -> vt[(b*16+h)*128 + d][s]   (LDS-tiled, swizzled)
__global__ __launch_bounds__(256) void transpose_v(const u16* __restrict__ qkv,
                                                   u16* __restrict__ vt) {
  __shared__ u16 lds[128 * 64];
  const int bh = blockIdx.y;
  const int b = bh >> 4, h = bh & 15;
  const int s0 = blockIdx.x * 64;
  const int t = threadIdx.x;
  union { uint4 v; u16 e[8]; } uu;
#pragma unroll
  for (int i = 0; i < 4; i++) {
    int s = i * 16 + (t >> 4);
    int dc = (t & 15) * 8;
    uu.v = *(const uint4*)(qkv + (size_t)(b * S_ + s0 + s) * NO_ + 4096 + h * 128 + dc);
#pragma unroll
    for (int q = 0; q < 8; q++) {
      int d = dc + q;
      lds[d * 64 + (s ^ (((d >> 3) & 7) << 3))] = uu.e[q];
    }
  }
  __syncthreads();
#pragma unroll
  for (int i = 0; i < 4; i++) {
    int d = i * 32 + (t >> 3);
    int sc = (t & 7) * 8;
    uint4 v = *(const uint4*)&lds[d * 64 + (sc ^ (((d >> 3) & 7) << 3))];
    *(uint4*)(vt + (size_t)(bh * 128 + d) * S_ + s0 + sc) = v;
  }
}

// ---------------------------------------------------------------- flash attention
// grid (S/64, B*H); 256 thr = 4 waves; wave w owns q rows [q0+16w, q0+16w+16).
// KV tile = 64. K tile [64][128] (4-bit XOR swizzle), V^T tile [128][64] (3-bit),
// P per wave [16][64] bf16 (3-bit swizzle). Online softmax in fp32.
__global__ __launch_bounds__(256) void flash_attn(const u16* __restrict__ qkv,
                                                  const u16* __restrict__ vt,
                                                  u16* __restrict__ ao) {
  __shared__ u16 lK[64 * 128];
  __shared__ u16 lV[128 * 64];
  __shared__ u16 lP[4][16 * 64];
  const int t = threadIdx.x;
  const int w = t >> 6, l = t & 63, lr = l & 15, lg = l >> 4;
  const int bh = blockIdx.y, b = bh >> 4, h = bh & 15;
  const int q0 = blockIdx.x * 64;
  u16* lPw = lP[w];

  // Q fragments (A operand): lane holds Q[lr][c*32 + lg*8 + e], scale pre-folded
  bf16x8 qf[4];
  {
    const u16* Qg = qkv + (size_t)(b * S_ + q0 + w * 16 + lr) * NO_ + h * 128;
#pragma unroll
    for (int c = 0; c < 4; c++) qf[c] = *(const bf16x8*)(Qg + c * 32 + lg * 8);
  }

  f32x4 acc[8] = {};
  float m_run[4] = {-INFINITY, -INFINITY, -INFINITY, -INFINITY};
  float l_run[4] = {0.f, 0.f, 0.f, 0.f};

  const int krow = t >> 4;   // 0..15
  const int kch = t & 15;    // 16B chunk in K row
  const int vdr = t >> 3;    // 0..31
  const int vch = t & 7;     // 16B chunk in V^T row

  for (int kt = 0; kt < S_ / 64; kt++) {
    const int kv0 = kt * 64;
    uint4 krg[4], vrg[4];
#pragma unroll
    for (int i = 0; i < 4; i++) {
      int r = i * 16 + krow;
      krg[i] = *(const uint4*)(qkv + (size_t)(b * S_ + kv0 + r) * NO_ + 2048 + h * 128 + kch * 8);
      int d = i * 32 + vdr;
      vrg[i] = *(const uint4*)(vt + (size_t)(bh * 128 + d) * S_ + kv0 + vch * 8);
    }
    __syncthreads();  // everyone done reading previous K/V tiles
#pragma unroll
    for (int i = 0; i < 4; i++) {
      int r = i * 16 + krow;
      *(uint4*)&lK[r * 128 + ((kch * 8) ^ ((r & 15) << 3))] = krg[i];
      int d = i * 32 + vdr;
      *(uint4*)&lV[d * 64 + ((vch * 8) ^ ((d & 7) << 3))] = vrg[i];
    }
    __syncthreads();  // tiles staged

    // ---- S = Q K^T (scaled): D row = q row (lg*4+j), col = kv pos (cb*16+lr)
    f32x4 sc[4] = {};
#pragma unroll
    for (int cb = 0; cb < 4; cb++) {
      int r = cb * 16 + lr;
#pragma unroll
      for (int c = 0; c < 4; c++) {
        bf16x8 kf = *(const bf16x8*)&lK[r * 128 + ((c * 32 + lg * 8) ^ ((r & 15) << 3))];
        sc[cb] = __builtin_amdgcn_mfma_f32_16x16x32_bf16(qf[c], kf, sc[cb], 0, 0, 0);
      }
    }

    // ---- online softmax over the 64 new columns
    float resc[4];
#pragma unroll
    for (int j = 0; j < 4; j++) {
      float v = fmaxf(fmaxf(sc[0][j], sc[1][j]), fmaxf(sc[2][j], sc[3][j]));
      v = fmaxf(v, __shfl_xor(v, 1));
      v = fmaxf(v, __shfl_xor(v, 2));
      v = fmaxf(v, __shfl_xor(v, 4));
      v = fmaxf(v, __shfl_xor(v, 8));
      float mn = fmaxf(m_run[j], v);
      resc[j] = __expf(m_run[j] - mn);
      m_run[j] = mn;
      float ps = 0.f;
#pragma unroll
      for (int cb = 0; cb < 4; cb++) {
        float p = __expf(sc[cb][j] - mn);
        sc[cb][j] = p;
        ps += p;
      }
      ps += __shfl_xor(ps, 1);
      ps += __shfl_xor(ps, 2);
      ps += __shfl_xor(ps, 4);
      ps += __shfl_xor(ps, 8);
      l_run[j] = l_run[j] * resc[j] + ps;
    }
#pragma unroll
    for (int nb = 0; nb < 8; nb++)
#pragma unroll
      for (int j = 0; j < 4; j++) acc[nb][j] *= resc[j];

    // ---- P -> LDS (bf16), wave-local
#pragma unroll
    for (int cb = 0; cb < 4; cb++)
#pragma unroll
      for (int j = 0; j < 4; j++) {
        int row = lg * 4 + j, colp = cb * 16 + lr;
        lPw[row * 64 + (colp ^ ((row & 7) << 3))] = f2bf(sc[cb][j]);
      }

    // ---- O += P V : A = P[16][64], B = V chunk (from V^T tile)
#pragma unroll
    for (int c2 = 0; c2 < 2; c2++) {
      bf16x8 pf = *(const bf16x8*)&lPw[lr * 64 + ((c2 * 32 + lg * 8) ^ ((lr & 7) << 3))];
#pragma unroll
      for (int nb = 0; nb < 8; nb++) {
        int r = nb * 16 + lr;
        bf16x8 vf = *(const bf16x8*)&lV[r * 64 + ((c2 * 32 + lg * 8) ^ ((r & 7) << 3))];
        acc[nb] = __builtin_amdgcn_mfma_f32_16x16x32_bf16(pf, vf, acc[nb], 0, 0, 0);
      }
    }
  }

  // ---- epilogue: normalize and write attn_out[b*S+q][h*128+d] bf16
  float linv[4];
#pragma unroll
  for (int j = 0; j < 4; j++) linv[j] = 1.0f / l_run[j];
#pragma unroll
  for (int nb = 0; nb < 8; nb++)
#pragma unroll
    for (int j = 0; j < 4; j++) {
      int qrow = q0 + w * 16 + lg * 4 + j;
      ao[(size_t)(b * S_ + qrow) * 2048 + h * 128 + nb * 16 + lr] = f2bf(acc[nb][j] * linv[j]);
    }
}

// ---------------------------------------------------------------- launch
extern "C" void kernel_launch(void* const* d_in, const int* in_sizes, int n_in,
                              void* d_out, int out_size, void* d_ws, size_t ws_size,
                              hipStream_t stream) {
  const float* x = (const float*)d_in[0];
  const float* wqkv = (const float*)d_in[1];
  const float* wout = (const float*)d_in[2];
  float* out = (float*)d_out;

  char* ws = (char*)d_ws;
  u16* xbf = (u16*)(ws);                              // 16 MiB (reused as attn_out)
  u16* wqkvb = (u16*)(ws + ((size_t)16 << 20));       // 24 MiB
  u16* woutb = (u16*)(ws + ((size_t)40 << 20));       // 8 MiB
  u16* qkv = (u16*)(ws + ((size_t)48 << 20));         // 48 MiB
  u16* vtb = (u16*)(ws + ((size_t)96 << 20));         // 16 MiB
  float* ct = (float*)(ws + ((size_t)112 << 20));     // 0.5 MiB
  float* st = (float*)(ws + ((size_t)112 << 20) + ((size_t)1 << 19));
  u16* aout = xbf;  // x_bf16 dead after gemm_qkv

  cvt_bf16<<<4096, 256, 0, stream>>>(x, xbf, M_ * DM_);
  cvt_bf16<<<4096, 256, 0, stream>>>(wqkv, wqkvb, NO_ * DM_);
  cvt_bf16<<<4096, 256, 0, stream>>>(wout, woutb, DM_ * DM_);
  rope_tables<<<(S_ * 64) / 256, 256, 0, stream>>>(ct, st);
  gemm_bt<1><<<dim3(NO_ / 128, M_ / 128), 256, 0, stream>>>(xbf, wqkvb, qkv, M_, NO_, DM_);
  rope_apply<<<(M_ * 32 * 64) / 256, 256, 0, stream>>>(qkv, ct, st);
  transpose_v<<<dim3(S_ / 64, B_ * H_), 256, 0, stream>>>(qkv, vtb);
  flash_attn<<<dim3(S_ / 64, B_ * H_), 256, 0, stream>>>(qkv, vtb, aout);
  gemm_bt<0><<<dim3(DM_ / 128, M_ / 128), 256, 0, stream>>>(aout, woutb, out, M_, DM_, DM_);
}

// Round 2
// 488.313 us; speedup vs baseline: 1.0766x; 1.0766x over previous
//
// Fused attention block (QKV proj + RoPE + flash attention + out proj), MI355X gfx950.
// R2: flash_attn K/V staging switched from reg round-trip (spilled: 850 MB scratch
// writes observed) to global_load_lds width-16 with pre-swizzled per-lane SOURCE
// addresses (linear LDS dest, same XOR involution on the read side).
// Workspace layout (needs ~113 MiB):
//   [0,16M)    x_bf16, later reused as attn_out
//   [16,40M)   w_qkv bf16
//   [40,48M)   w_out bf16
//   [48,96M)   qkv   bf16 [4096][6144]
//   [96,112M)  v^T   bf16 [32*128][2048]
//   [112M,..)  cos/sin tables fp32 [2048][64] each

#include <hip/hip_runtime.h>
#include <math.h>
#include <stdint.h>

typedef unsigned short u16;
typedef unsigned int u32;
typedef float f32x4 __attribute__((ext_vector_type(4)));
typedef __bf16 bf16x8 __attribute__((ext_vector_type(8)));

typedef const __attribute__((address_space(1))) u32* gas1;
typedef __attribute__((address_space(3))) u32* las3;

#define B_ 2
#define S_ 2048
#define DM_ 2048
#define H_ 16
#define HD_ 128
#define NO_ 6144
#define M_ 4096

__device__ __forceinline__ u16 f2bf(float f) {
  u32 u = __float_as_uint(f);
  u32 r = (u + 0x7fffu + ((u >> 16) & 1u)) >> 16;  // RNE
  return (u16)r;
}
__device__ __forceinline__ float bf2f(u16 h) {
  return __uint_as_float(((u32)h) << 16);
}

// ---------------------------------------------------------------- convert
__global__ void cvt_bf16(const float* __restrict__ in, u16* __restrict__ out, int n) {
  int i = (blockIdx.x * blockDim.x + threadIdx.x) * 4;
  int stride = gridDim.x * blockDim.x * 4;
  for (; i < n; i += stride) {
    float4 v = *(const float4*)(in + i);
    ushort4 o;
    o.x = f2bf(v.x); o.y = f2bf(v.y); o.z = f2bf(v.z); o.w = f2bf(v.w);
    *(ushort4*)(out + i) = o;
  }
}

// ---------------------------------------------------------------- rope tables
__global__ void rope_tables(float* __restrict__ ct, float* __restrict__ st) {
  int i = blockIdx.x * blockDim.x + threadIdx.x;  // S_*64 threads
  int s = i >> 6, j = i & 63;
  float inv = powf(10000.0f, -(float)j / 64.0f);
  float f = (float)s * inv;
  ct[i] = cosf(f);
  st[i] = sinf(f);
}

// ---------------------------------------------------------------- GEMM  C = A * B^T
// A [M][K] bf16 row-major, B [N][K] bf16 row-major (B^T layout), both K%32==0.
// m97 structure: 128x128 tile, BK=32, 256 thr (4 waves, 2x2), 4x4 16x16x32 frags/wave,
// global_load_lds width 16, 2 barriers per K-step.
template <int OUT_BF16>
__global__ __launch_bounds__(256) void gemm_bt(const u16* __restrict__ A,
                                               const u16* __restrict__ B,
                                               void* __restrict__ Cv,
                                               int M, int N, int K) {
  __shared__ u16 lA[128 * 32];
  __shared__ u16 lB[128 * 32];
  const int t = threadIdx.x;
  const int m0 = blockIdx.y * 128, n0 = blockIdx.x * 128;
  const int w = t >> 6, l = t & 63, lr = l & 15, lg = l >> 4;
  const int wm = (w >> 1) * 64, wn = (w & 1) * 64;
  f32x4 acc[4][4] = {};
  const int srow = t >> 2;       // staging row 0..63 (per round)
  const int scol = (t & 3) * 8;  // staging col chunk
  const u16* Ag = A + (size_t)(m0 + srow) * K + scol;
  const u16* Bg = B + (size_t)(n0 + srow) * K + scol;

  for (int k0 = 0; k0 < K; k0 += 32) {
    __syncthreads();  // previous tile fully consumed
#pragma unroll
    for (int i = 0; i < 2; i++) {
      __builtin_amdgcn_global_load_lds((gas1)(Ag + (size_t)i * 64 * K + k0),
                                       (las3)(lA + (i * 256 + w * 64) * 8), 16, 0, 0);
      __builtin_amdgcn_global_load_lds((gas1)(Bg + (size_t)i * 64 * K + k0),
                                       (las3)(lB + (i * 256 + w * 64) * 8), 16, 0, 0);
    }
    __syncthreads();  // staged tile visible
    bf16x8 af[4], bfr[4];
#pragma unroll
    for (int mi = 0; mi < 4; mi++)
      af[mi] = *(const bf16x8*)&lA[(wm + mi * 16 + lr) * 32 + lg * 8];
#pragma unroll
    for (int ni = 0; ni < 4; ni++)
      bfr[ni] = *(const bf16x8*)&lB[(wn + ni * 16 + lr) * 32 + lg * 8];
#pragma unroll
    for (int mi = 0; mi < 4; mi++)
#pragma unroll
      for (int ni = 0; ni < 4; ni++)
        acc[mi][ni] =
            __builtin_amdgcn_mfma_f32_16x16x32_bf16(af[mi], bfr[ni], acc[mi][ni], 0, 0, 0);
  }

  // epilogue: D row=(lane>>4)*4+j, col=lane&15 (m89/m91-verified layout)
#pragma unroll
  for (int mi = 0; mi < 4; mi++)
#pragma unroll
    for (int ni = 0; ni < 4; ni++) {
      int row = m0 + wm + mi * 16 + lg * 4;
      int col = n0 + wn + ni * 16 + lr;
      if (OUT_BF16) {
        u16* C = (u16*)Cv;
#pragma unroll
        for (int j = 0; j < 4; j++) C[(size_t)(row + j) * N + col] = f2bf(acc[mi][ni][j]);
      } else {
        float* C = (float*)Cv;
#pragma unroll
        for (int j = 0; j < 4; j++) C[(size_t)(row + j) * N + col] = acc[mi][ni][j];
      }
    }
}

// ---------------------------------------------------------------- RoPE in place on q,k
// thread -> (row=b*S+s, hh in [0,32): 0-15 q heads, 16-31 k heads, j in [0,64))
// out[j]    = e1*cos - e2*sin ;  out[j+64] = e2*cos + e1*sin ;  q also * 1/sqrt(128)
__global__ void rope_apply(u16* __restrict__ qkv, const float* __restrict__ ct,
                           const float* __restrict__ st) {
  int i = blockIdx.x * blockDim.x + threadIdx.x;  // M_*32*64 threads
  int j = i & 63;
  int hh = (i >> 6) & 31;
  int row = i >> 11;
  int s = row & (S_ - 1);
  int col = (hh < 16) ? hh * 128 : 2048 + (hh - 16) * 128;
  u16* p = qkv + (size_t)row * NO_ + col + j;
  float e1 = bf2f(p[0]), e2 = bf2f(p[64]);
  float c = ct[(s << 6) + j], sn = st[(s << 6) + j];
  float o1 = e1 * c - e2 * sn;
  float o2 = e2 * c + e1 * sn;
  if (hh < 16) {  // fold softmax scale into q (commutes with rotation)
    o1 *= 0.08838834764831845f;
    o2 *= 0.08838834764831845f;
  }
  p[0] = f2bf(o1);
  p[64] = f2bf(o2);
}

// ---------------------------------------------------------------- V transpose
// qkv[b*S+s][4096 + h*128 + d] -> vt[(b*16+h)*128 + d][s]   (LDS-tiled, swizzled)
__global__ __launch_bounds__(256) void transpose_v(const u16* __restrict__ qkv,
                                                   u16* __restrict__ vt) {
  __shared__ u16 lds[128 * 64];
  const int bh = blockIdx.y;
  const int b = bh >> 4, h = bh & 15;
  const int s0 = blockIdx.x * 64;
  const int t = threadIdx.x;
  union { uint4 v; u16 e[8]; } uu;
#pragma unroll
  for (int i = 0; i < 4; i++) {
    int s = i * 16 + (t >> 4);
    int dc = (t & 15) * 8;
    uu.v = *(const uint4*)(qkv + (size_t)(b * S_ + s0 + s) * NO_ + 4096 + h * 128 + dc);
#pragma unroll
    for (int q = 0; q < 8; q++) {
      int d = dc + q;
      lds[d * 64 + (s ^ (((d >> 3) & 7) << 3))] = uu.e[q];
    }
  }
  __syncthreads();
#pragma unroll
  for (int i = 0; i < 4; i++) {
    int d = i * 32 + (t >> 3);
    int sc = (t & 7) * 8;
    uint4 v = *(const uint4*)&lds[d * 64 + (sc ^ (((d >> 3) & 7) << 3))];
    *(uint4*)(vt + (size_t)(bh * 128 + d) * S_ + s0 + sc) = v;
  }
}

// ---------------------------------------------------------------- flash attention
// grid (S/64, B*H); 256 thr = 4 waves; wave w owns q rows [q0+16w, q0+16w+16).
// KV tile = 64. K tile [64][128] (4-bit XOR chunk swizzle), V^T tile [128][64]
// (3-bit), both staged via global_load_lds with pre-swizzled per-lane SOURCE
// chunk (LDS dest linear; read side applies the same involution).
// P per wave [16][64] bf16 (3-bit swizzle). Online softmax in fp32.
__global__ __launch_bounds__(256) void flash_attn(const u16* __restrict__ qkv,
                                                  const u16* __restrict__ vt,
                                                  u16* __restrict__ ao) {
  __shared__ u16 lK[64 * 128];
  __shared__ u16 lV[128 * 64];
  __shared__ u16 lP[4][16 * 64];
  const int t = threadIdx.x;
  const int w = t >> 6, l = t & 63, lr = l & 15, lg = l >> 4;
  const int bh = blockIdx.y, b = bh >> 4, h = bh & 15;
  const int q0 = blockIdx.x * 64;
  u16* lPw = lP[w];

  // Q fragments (A operand): lane holds Q[lr][c*32 + lg*8 + e], scale pre-folded
  bf16x8 qf[4];
  {
    const u16* Qg = qkv + (size_t)(b * S_ + q0 + w * 16 + lr) * NO_ + h * 128;
#pragma unroll
    for (int c = 0; c < 4; c++) qf[c] = *(const bf16x8*)(Qg + c * 32 + lg * 8);
  }

  f32x4 acc[8] = {};
  float m_run[4] = {-INFINITY, -INFINITY, -INFINITY, -INFINITY};
  float l_run[4] = {0.f, 0.f, 0.f, 0.f};

  // ---- staging source pointers (advance per tile). Wave w stages:
  //  K rows  [w*16 + q*4 + (l>>4)],  dest chunk l&15, src chunk = (l&15) ^ (r&15)
  //  V rows  [w*32 + q*8 + (l>>3)],  dest chunk l&7,  src chunk = (l&7) ^ (d&7)
  const u16* ksrc[4];
  const u16* vsrc[4];
#pragma unroll
  for (int q = 0; q < 4; q++) {
    int rt = w * 16 + q * 4 + (l >> 4);            // row within K tile
    int ck = (l & 15) ^ (rt & 15);                 // pre-swizzled source chunk
    ksrc[q] = qkv + (size_t)(b * S_ + rt) * NO_ + 2048 + h * 128 + ck * 8;
    int d = w * 32 + q * 8 + (l >> 3);             // row within V^T tile (d dim)
    int cv = (l & 7) ^ (d & 7);
    vsrc[q] = vt + (size_t)(bh * 128 + d) * S_ + cv * 8;
  }

  for (int kt = 0; kt < S_ / 64; kt++) {
    __syncthreads();  // everyone done reading previous K/V tiles
#pragma unroll
    for (int q = 0; q < 4; q++) {
      __builtin_amdgcn_global_load_lds((gas1)ksrc[q],
                                       (las3)(lK + (w * 16 + q * 4) * 128), 16, 0, 0);
      __builtin_amdgcn_global_load_lds((gas1)vsrc[q],
                                       (las3)(lV + (w * 32 + q * 8) * 64), 16, 0, 0);
      ksrc[q] += (size_t)64 * NO_;  // next KV tile: +64 rows
      vsrc[q] += 64;                // next KV tile: +64 cols of V^T
    }
    __syncthreads();  // tiles staged (compiler drains vmcnt before barrier)

    // ---- S = Q K^T (scaled): D row = q row (lg*4+j), col = kv pos (cb*16+lr)
    f32x4 sc[4] = {};
#pragma unroll
    for (int cb = 0; cb < 4; cb++) {
      int r = cb * 16 + lr;
#pragma unroll
      for (int c = 0; c < 4; c++) {
        bf16x8 kf = *(const bf16x8*)&lK[r * 128 + ((c * 32 + lg * 8) ^ ((r & 15) << 3))];
        sc[cb] = __builtin_amdgcn_mfma_f32_16x16x32_bf16(qf[c], kf, sc[cb], 0, 0, 0);
      }
    }

    // ---- online softmax over the 64 new columns
    float resc[4];
#pragma unroll
    for (int j = 0; j < 4; j++) {
      float v = fmaxf(fmaxf(sc[0][j], sc[1][j]), fmaxf(sc[2][j], sc[3][j]));
      v = fmaxf(v, __shfl_xor(v, 1));
      v = fmaxf(v, __shfl_xor(v, 2));
      v = fmaxf(v, __shfl_xor(v, 4));
      v = fmaxf(v, __shfl_xor(v, 8));
      float mn = fmaxf(m_run[j], v);
      resc[j] = __expf(m_run[j] - mn);
      m_run[j] = mn;
      float ps = 0.f;
#pragma unroll
      for (int cb = 0; cb < 4; cb++) {
        float p = __expf(sc[cb][j] - mn);
        sc[cb][j] = p;
        ps += p;
      }
      ps += __shfl_xor(ps, 1);
      ps += __shfl_xor(ps, 2);
      ps += __shfl_xor(ps, 4);
      ps += __shfl_xor(ps, 8);
      l_run[j] = l_run[j] * resc[j] + ps;
    }
#pragma unroll
    for (int nb = 0; nb < 8; nb++)
#pragma unroll
      for (int j = 0; j < 4; j++) acc[nb][j] *= resc[j];

    // ---- P -> LDS (bf16), wave-local
#pragma unroll
    for (int cb = 0; cb < 4; cb++)
#pragma unroll
      for (int j = 0; j < 4; j++) {
        int row = lg * 4 + j, colp = cb * 16 + lr;
        lPw[row * 64 + (colp ^ ((row & 7) << 3))] = f2bf(sc[cb][j]);
      }

    // ---- O += P V : A = P[16][64], B = V chunk (from V^T tile)
#pragma unroll
    for (int c2 = 0; c2 < 2; c2++) {
      bf16x8 pf = *(const bf16x8*)&lPw[lr * 64 + ((c2 * 32 + lg * 8) ^ ((lr & 7) << 3))];
#pragma unroll
      for (int nb = 0; nb < 8; nb++) {
        int r = nb * 16 + lr;
        bf16x8 vf = *(const bf16x8*)&lV[r * 64 + ((c2 * 32 + lg * 8) ^ ((r & 7) << 3))];
        acc[nb] = __builtin_amdgcn_mfma_f32_16x16x32_bf16(pf, vf, acc[nb], 0, 0, 0);
      }
    }
  }

  // ---- epilogue: normalize and write attn_out[b*S+q][h*128+d] bf16
  float linv[4];
#pragma unroll
  for (int j = 0; j < 4; j++) linv[j] = 1.0f / l_run[j];
#pragma unroll
  for (int nb = 0; nb < 8; nb++)
#pragma unroll
    for (int j = 0; j < 4; j++) {
      int qrow = q0 + w * 16 + lg * 4 + j;
      ao[(size_t)(b * S_ + qrow) * 2048 + h * 128 + nb * 16 + lr] = f2bf(acc[nb][j] * linv[j]);
    }
}

// ---------------------------------------------------------------- launch
extern "C" void kernel_launch(void* const* d_in, const int* in_sizes, int n_in,
                              void* d_out, int out_size, void* d_ws, size_t ws_size,
                              hipStream_t stream) {
  const float* x = (const float*)d_in[0];
  const float* wqkv = (const float*)d_in[1];
  const float* wout = (const float*)d_in[2];
  float* out = (float*)d_out;

  char* ws = (char*)d_ws;
  u16* xbf = (u16*)(ws);                              // 16 MiB (reused as attn_out)
  u16* wqkvb = (u16*)(ws + ((size_t)16 << 20));       // 24 MiB
  u16* woutb = (u16*)(ws + ((size_t)40 << 20));       // 8 MiB
  u16* qkv = (u16*)(ws + ((size_t)48 << 20));         // 48 MiB
  u16* vtb = (u16*)(ws + ((size_t)96 << 20));         // 16 MiB
  float* ct = (float*)(ws + ((size_t)112 << 20));     // 0.5 MiB
  float* st = (float*)(ws + ((size_t)112 << 20) + ((size_t)1 << 19));
  u16* aout = xbf;  // x_bf16 dead after gemm_qkv

  cvt_bf16<<<4096, 256, 0, stream>>>(x, xbf, M_ * DM_);
  cvt_bf16<<<4096, 256, 0, stream>>>(wqkv, wqkvb, NO_ * DM_);
  cvt_bf16<<<4096, 256, 0, stream>>>(wout, woutb, DM_ * DM_);
  rope_tables<<<(S_ * 64) / 256, 256, 0, stream>>>(ct, st);
  gemm_bt<1><<<dim3(NO_ / 128, M_ / 128), 256, 0, stream>>>(xbf, wqkvb, qkv, M_, NO_, DM_);
  rope_apply<<<(M_ * 32 * 64) / 256, 256, 0, stream>>>(qkv, ct, st);
  transpose_v<<<dim3(S_ / 64, B_ * H_), 256, 0, stream>>>(qkv, vtb);
  flash_attn<<<dim3(S_ / 64, B_ * H_), 256, 0, stream>>>(qkv, vtb, aout);
  gemm_bt<0><<<dim3(DM_ / 128, M_ / 128), 256, 0, stream>>>(aout, woutb, out, M_, DM_, DM_);
}

// Round 3
// 415.759 us; speedup vs baseline: 1.2644x; 1.1745x over previous
//
// Fused attention block (QKV proj + RoPE + flash attention + out proj), MI355X gfx950.
// R3: flash_attn double-buffered K/V staging (T3-minimum 2-phase: issue next tile's
// global_load_lds BEFORE compute so the vmcnt(0)-before-barrier drain is covered by
// ~2000 cycles of QK^T/softmax/PV). Softmax in log2 domain (log2e folded into q
// scale, exp2f) + T13 defer-max (skip acc rescale when tile max grows < 10).
// Workspace layout (needs ~113 MiB):
//   [0,16M)    x_bf16, later reused as attn_out
//   [16,40M)   w_qkv bf16
//   [40,48M)   w_out bf16
//   [48,96M)   qkv   bf16 [4096][6144]
//   [96,112M)  v^T   bf16 [32*128][2048]
//   [112M,..)  cos/sin tables fp32 [2048][64] each

#include <hip/hip_runtime.h>
#include <math.h>
#include <stdint.h>

typedef unsigned short u16;
typedef unsigned int u32;
typedef float f32x4 __attribute__((ext_vector_type(4)));
typedef __bf16 bf16x8 __attribute__((ext_vector_type(8)));

typedef const __attribute__((address_space(1))) u32* gas1;
typedef __attribute__((address_space(3))) u32* las3;

#define B_ 2
#define S_ 2048
#define DM_ 2048
#define H_ 16
#define HD_ 128
#define NO_ 6144
#define M_ 4096

__device__ __forceinline__ u16 f2bf(float f) {
  u32 u = __float_as_uint(f);
  u32 r = (u + 0x7fffu + ((u >> 16) & 1u)) >> 16;  // RNE
  return (u16)r;
}
__device__ __forceinline__ float bf2f(u16 h) {
  return __uint_as_float(((u32)h) << 16);
}

// ---------------------------------------------------------------- convert
__global__ void cvt_bf16(const float* __restrict__ in, u16* __restrict__ out, int n) {
  int i = (blockIdx.x * blockDim.x + threadIdx.x) * 4;
  int stride = gridDim.x * blockDim.x * 4;
  for (; i < n; i += stride) {
    float4 v = *(const float4*)(in + i);
    ushort4 o;
    o.x = f2bf(v.x); o.y = f2bf(v.y); o.z = f2bf(v.z); o.w = f2bf(v.w);
    *(ushort4*)(out + i) = o;
  }
}

// ---------------------------------------------------------------- rope tables
__global__ void rope_tables(float* __restrict__ ct, float* __restrict__ st) {
  int i = blockIdx.x * blockDim.x + threadIdx.x;  // S_*64 threads
  int s = i >> 6, j = i & 63;
  float inv = powf(10000.0f, -(float)j / 64.0f);
  float f = (float)s * inv;
  ct[i] = cosf(f);
  st[i] = sinf(f);
}

// ---------------------------------------------------------------- GEMM  C = A * B^T
// A [M][K] bf16 row-major, B [N][K] bf16 row-major (B^T layout), both K%32==0.
// m97 structure: 128x128 tile, BK=32, 256 thr (4 waves, 2x2), 4x4 16x16x32 frags/wave,
// global_load_lds width 16, 2 barriers per K-step.
template <int OUT_BF16>
__global__ __launch_bounds__(256) void gemm_bt(const u16* __restrict__ A,
                                               const u16* __restrict__ B,
                                               void* __restrict__ Cv,
                                               int M, int N, int K) {
  __shared__ u16 lA[128 * 32];
  __shared__ u16 lB[128 * 32];
  const int t = threadIdx.x;
  const int m0 = blockIdx.y * 128, n0 = blockIdx.x * 128;
  const int w = t >> 6, l = t & 63, lr = l & 15, lg = l >> 4;
  const int wm = (w >> 1) * 64, wn = (w & 1) * 64;
  f32x4 acc[4][4] = {};
  const int srow = t >> 2;       // staging row 0..63 (per round)
  const int scol = (t & 3) * 8;  // staging col chunk
  const u16* Ag = A + (size_t)(m0 + srow) * K + scol;
  const u16* Bg = B + (size_t)(n0 + srow) * K + scol;

  for (int k0 = 0; k0 < K; k0 += 32) {
    __syncthreads();  // previous tile fully consumed
#pragma unroll
    for (int i = 0; i < 2; i++) {
      __builtin_amdgcn_global_load_lds((gas1)(Ag + (size_t)i * 64 * K + k0),
                                       (las3)(lA + (i * 256 + w * 64) * 8), 16, 0, 0);
      __builtin_amdgcn_global_load_lds((gas1)(Bg + (size_t)i * 64 * K + k0),
                                       (las3)(lB + (i * 256 + w * 64) * 8), 16, 0, 0);
    }
    __syncthreads();  // staged tile visible
    bf16x8 af[4], bfr[4];
#pragma unroll
    for (int mi = 0; mi < 4; mi++)
      af[mi] = *(const bf16x8*)&lA[(wm + mi * 16 + lr) * 32 + lg * 8];
#pragma unroll
    for (int ni = 0; ni < 4; ni++)
      bfr[ni] = *(const bf16x8*)&lB[(wn + ni * 16 + lr) * 32 + lg * 8];
#pragma unroll
    for (int mi = 0; mi < 4; mi++)
#pragma unroll
      for (int ni = 0; ni < 4; ni++)
        acc[mi][ni] =
            __builtin_amdgcn_mfma_f32_16x16x32_bf16(af[mi], bfr[ni], acc[mi][ni], 0, 0, 0);
  }

  // epilogue: D row=(lane>>4)*4+j, col=lane&15 (m89/m91-verified layout)
#pragma unroll
  for (int mi = 0; mi < 4; mi++)
#pragma unroll
    for (int ni = 0; ni < 4; ni++) {
      int row = m0 + wm + mi * 16 + lg * 4;
      int col = n0 + wn + ni * 16 + lr;
      if (OUT_BF16) {
        u16* C = (u16*)Cv;
#pragma unroll
        for (int j = 0; j < 4; j++) C[(size_t)(row + j) * N + col] = f2bf(acc[mi][ni][j]);
      } else {
        float* C = (float*)Cv;
#pragma unroll
        for (int j = 0; j < 4; j++) C[(size_t)(row + j) * N + col] = acc[mi][ni][j];
      }
    }
}

// ---------------------------------------------------------------- RoPE in place on q,k
// thread -> (row=b*S+s, hh in [0,32): 0-15 q heads, 16-31 k heads, j in [0,64))
// out[j]    = e1*cos - e2*sin ;  out[j+64] = e2*cos + e1*sin
// q additionally scaled by (1/sqrt(128)) * log2(e)  -> softmax runs in log2 domain.
__global__ void rope_apply(u16* __restrict__ qkv, const float* __restrict__ ct,
                           const float* __restrict__ st) {
  int i = blockIdx.x * blockDim.x + threadIdx.x;  // M_*32*64 threads
  int j = i & 63;
  int hh = (i >> 6) & 31;
  int row = i >> 11;
  int s = row & (S_ - 1);
  int col = (hh < 16) ? hh * 128 : 2048 + (hh - 16) * 128;
  u16* p = qkv + (size_t)row * NO_ + col + j;
  float e1 = bf2f(p[0]), e2 = bf2f(p[64]);
  float c = ct[(s << 6) + j], sn = st[(s << 6) + j];
  float o1 = e1 * c - e2 * sn;
  float o2 = e2 * c + e1 * sn;
  if (hh < 16) {  // fold softmax scale * log2(e) into q
    const float kq = 0.08838834764831845f * 1.4426950408889634f;
    o1 *= kq;
    o2 *= kq;
  }
  p[0] = f2bf(o1);
  p[64] = f2bf(o2);
}

// ---------------------------------------------------------------- V transpose
// qkv[b*S+s][4096 + h*128 + d] -> vt[(b*16+h)*128 + d][s]   (LDS-tiled, swizzled)
__global__ __launch_bounds__(256) void transpose_v(const u16* __restrict__ qkv,
                                                   u16* __restrict__ vt) {
  __shared__ u16 lds[128 * 64];
  const int bh = blockIdx.y;
  const int b = bh >> 4, h = bh & 15;
  const int s0 = blockIdx.x * 64;
  const int t = threadIdx.x;
  union { uint4 v; u16 e[8]; } uu;
#pragma unroll
  for (int i = 0; i < 4; i++) {
    int s = i * 16 + (t >> 4);
    int dc = (t & 15) * 8;
    uu.v = *(const uint4*)(qkv + (size_t)(b * S_ + s0 + s) * NO_ + 4096 + h * 128 + dc);
#pragma unroll
    for (int q = 0; q < 8; q++) {
      int d = dc + q;
      lds[d * 64 + (s ^ (((d >> 3) & 7) << 3))] = uu.e[q];
    }
  }
  __syncthreads();
#pragma unroll
  for (int i = 0; i < 4; i++) {
    int d = i * 32 + (t >> 3);
    int sc = (t & 7) * 8;
    uint4 v = *(const uint4*)&lds[d * 64 + (sc ^ (((d >> 3) & 7) << 3))];
    *(uint4*)(vt + (size_t)(bh * 128 + d) * S_ + s0 + sc) = v;
  }
}

// ---------------------------------------------------------------- flash attention
// grid (S/64, B*H); 256 thr = 4 waves; wave w owns q rows [q0+16w, q0+16w+16).
// KV tile = 64, double-buffered: stage(t+1) issued before compute(t); the single
// end-of-iteration barrier's vmcnt(0) drain is covered by the compute phase.
// K tile [64][128] (4-bit XOR chunk swizzle), V^T tile [128][64] (3-bit), staged via
// global_load_lds with pre-swizzled per-lane SOURCE chunk (LDS dest linear).
// P per wave [16][64] bf16 (3-bit swizzle). Online softmax fp32, log2 domain,
// defer-max (THR=10): P bounded by 2^10, consistent l/acc scaling.
__global__ __launch_bounds__(256) void flash_attn(const u16* __restrict__ qkv,
                                                  const u16* __restrict__ vt,
                                                  u16* __restrict__ ao) {
  __shared__ u16 lK[2][64 * 128];
  __shared__ u16 lV[2][128 * 64];
  __shared__ u16 lP[4][16 * 64];
  const int t = threadIdx.x;
  const int w = t >> 6, l = t & 63, lr = l & 15, lg = l >> 4;
  const int bh = blockIdx.y, b = bh >> 4, h = bh & 15;
  const int q0 = blockIdx.x * 64;
  u16* lPw = lP[w];

  // Q fragments (A operand): lane holds Q[lr][c*32 + lg*8 + e], scale pre-folded
  bf16x8 qf[4];
  {
    const u16* Qg = qkv + (size_t)(b * S_ + q0 + w * 16 + lr) * NO_ + h * 128;
#pragma unroll
    for (int c = 0; c < 4; c++) qf[c] = *(const bf16x8*)(Qg + c * 32 + lg * 8);
  }

  f32x4 acc[8] = {};
  float m_run[4] = {-INFINITY, -INFINITY, -INFINITY, -INFINITY};
  float l_run[4] = {0.f, 0.f, 0.f, 0.f};

  // ---- staging source pointers (advance one tile per issue). Wave w stages:
  //  K rows  [w*16 + q*4 + (l>>4)],  dest chunk l&15, src chunk = (l&15) ^ (r&15)
  //  V rows  [w*32 + q*8 + (l>>3)],  dest chunk l&7,  src chunk = (l&7) ^ (d&7)
  const u16* ksrc[4];
  const u16* vsrc[4];
#pragma unroll
  for (int q = 0; q < 4; q++) {
    int rt = w * 16 + q * 4 + (l >> 4);            // row within K tile
    int ck = (l & 15) ^ (rt & 15);                 // pre-swizzled source chunk
    ksrc[q] = qkv + (size_t)(b * S_ + rt) * NO_ + 2048 + h * 128 + ck * 8;
    int d = w * 32 + q * 8 + (l >> 3);             // row within V^T tile (d dim)
    int cv = (l & 7) ^ (d & 7);
    vsrc[q] = vt + (size_t)(bh * 128 + d) * S_ + cv * 8;
  }

  // ---- prologue: stage tile 0 into buffer 0
#pragma unroll
  for (int q = 0; q < 4; q++) {
    __builtin_amdgcn_global_load_lds((gas1)ksrc[q],
                                     (las3)(lK[0] + (w * 16 + q * 4) * 128), 16, 0, 0);
    __builtin_amdgcn_global_load_lds((gas1)vsrc[q],
                                     (las3)(lV[0] + (w * 32 + q * 8) * 64), 16, 0, 0);
    ksrc[q] += (size_t)64 * NO_;
    vsrc[q] += 64;
  }
  __syncthreads();  // buffer 0 staged

  const int NT = S_ / 64;
  for (int kt = 0; kt < NT; kt++) {
    const int cur = kt & 1;
    // ---- issue next tile's staging into the other buffer (latency hidden by compute)
    if (kt + 1 < NT) {
#pragma unroll
      for (int q = 0; q < 4; q++) {
        __builtin_amdgcn_global_load_lds((gas1)ksrc[q],
                                         (las3)(lK[cur ^ 1] + (w * 16 + q * 4) * 128), 16, 0, 0);
        __builtin_amdgcn_global_load_lds((gas1)vsrc[q],
                                         (las3)(lV[cur ^ 1] + (w * 32 + q * 8) * 64), 16, 0, 0);
        ksrc[q] += (size_t)64 * NO_;
        vsrc[q] += 64;
      }
    }

    // ---- S = Q K^T (log2 domain): D row = q row (lg*4+j), col = kv pos (cb*16+lr)
    f32x4 sc[4] = {};
#pragma unroll
    for (int cb = 0; cb < 4; cb++) {
      int r = cb * 16 + lr;
#pragma unroll
      for (int c = 0; c < 4; c++) {
        bf16x8 kf = *(const bf16x8*)&lK[cur][r * 128 + ((c * 32 + lg * 8) ^ ((r & 15) << 3))];
        sc[cb] = __builtin_amdgcn_mfma_f32_16x16x32_bf16(qf[c], kf, sc[cb], 0, 0, 0);
      }
    }

    // ---- online softmax (log2 domain) with defer-max
    float tmax[4];
#pragma unroll
    for (int j = 0; j < 4; j++) {
      float v = fmaxf(fmaxf(sc[0][j], sc[1][j]), fmaxf(sc[2][j], sc[3][j]));
      v = fmaxf(v, __shfl_xor(v, 1));
      v = fmaxf(v, __shfl_xor(v, 2));
      v = fmaxf(v, __shfl_xor(v, 4));
      v = fmaxf(v, __shfl_xor(v, 8));
      tmax[j] = v;
    }
    bool ok = true;
#pragma unroll
    for (int j = 0; j < 4; j++) ok &= (tmax[j] <= m_run[j] + 10.0f);
    if (!__all(ok)) {
      float resc[4];
#pragma unroll
      for (int j = 0; j < 4; j++) {
        float mn = fmaxf(m_run[j], tmax[j]);
        resc[j] = exp2f(m_run[j] - mn);
        m_run[j] = mn;
        l_run[j] *= resc[j];
      }
#pragma unroll
      for (int nb = 0; nb < 8; nb++)
#pragma unroll
        for (int j = 0; j < 4; j++) acc[nb][j] *= resc[j];
    }
#pragma unroll
    for (int j = 0; j < 4; j++) {
      float ps = 0.f;
#pragma unroll
      for (int cb = 0; cb < 4; cb++) {
        float p = exp2f(sc[cb][j] - m_run[j]);
        sc[cb][j] = p;
        ps += p;
      }
      ps += __shfl_xor(ps, 1);
      ps += __shfl_xor(ps, 2);
      ps += __shfl_xor(ps, 4);
      ps += __shfl_xor(ps, 8);
      l_run[j] += ps;
    }

    // ---- P -> LDS (bf16), wave-local
#pragma unroll
    for (int cb = 0; cb < 4; cb++)
#pragma unroll
      for (int j = 0; j < 4; j++) {
        int row = lg * 4 + j, colp = cb * 16 + lr;
        lPw[row * 64 + (colp ^ ((row & 7) << 3))] = f2bf(sc[cb][j]);
      }

    // ---- O += P V : A = P[16][64], B = V chunk (from V^T tile)
#pragma unroll
    for (int c2 = 0; c2 < 2; c2++) {
      bf16x8 pf = *(const bf16x8*)&lPw[lr * 64 + ((c2 * 32 + lg * 8) ^ ((lr & 7) << 3))];
#pragma unroll
      for (int nb = 0; nb < 8; nb++) {
        int r = nb * 16 + lr;
        bf16x8 vf = *(const bf16x8*)&lV[cur][r * 64 + ((c2 * 32 + lg * 8) ^ ((r & 7) << 3))];
        acc[nb] = __builtin_amdgcn_mfma_f32_16x16x32_bf16(pf, vf, acc[nb], 0, 0, 0);
      }
    }

    __syncthreads();  // drains next-tile staging (covered by compute) + frees cur
  }

  // ---- epilogue: normalize and write attn_out[b*S+q][h*128+d] bf16
  float linv[4];
#pragma unroll
  for (int j = 0; j < 4; j++) linv[j] = 1.0f / l_run[j];
#pragma unroll
  for (int nb = 0; nb < 8; nb++)
#pragma unroll
    for (int j = 0; j < 4; j++) {
      int qrow = q0 + w * 16 + lg * 4 + j;
      ao[(size_t)(b * S_ + qrow) * 2048 + h * 128 + nb * 16 + lr] = f2bf(acc[nb][j] * linv[j]);
    }
}

// ---------------------------------------------------------------- launch
extern "C" void kernel_launch(void* const* d_in, const int* in_sizes, int n_in,
                              void* d_out, int out_size, void* d_ws, size_t ws_size,
                              hipStream_t stream) {
  const float* x = (const float*)d_in[0];
  const float* wqkv = (const float*)d_in[1];
  const float* wout = (const float*)d_in[2];
  float* out = (float*)d_out;

  char* ws = (char*)d_ws;
  u16* xbf = (u16*)(ws);                              // 16 MiB (reused as attn_out)
  u16* wqkvb = (u16*)(ws + ((size_t)16 << 20));       // 24 MiB
  u16* woutb = (u16*)(ws + ((size_t)40 << 20));       // 8 MiB
  u16* qkv = (u16*)(ws + ((size_t)48 << 20));         // 48 MiB
  u16* vtb = (u16*)(ws + ((size_t)96 << 20));         // 16 MiB
  float* ct = (float*)(ws + ((size_t)112 << 20));     // 0.5 MiB
  float* st = (float*)(ws + ((size_t)112 << 20) + ((size_t)1 << 19));
  u16* aout = xbf;  // x_bf16 dead after gemm_qkv

  cvt_bf16<<<4096, 256, 0, stream>>>(x, xbf, M_ * DM_);
  cvt_bf16<<<4096, 256, 0, stream>>>(wqkv, wqkvb, NO_ * DM_);
  cvt_bf16<<<4096, 256, 0, stream>>>(wout, woutb, DM_ * DM_);
  rope_tables<<<(S_ * 64) / 256, 256, 0, stream>>>(ct, st);
  gemm_bt<1><<<dim3(NO_ / 128, M_ / 128), 256, 0, stream>>>(xbf, wqkvb, qkv, M_, NO_, DM_);
  rope_apply<<<(M_ * 32 * 64) / 256, 256, 0, stream>>>(qkv, ct, st);
  transpose_v<<<dim3(S_ / 64, B_ * H_), 256, 0, stream>>>(qkv, vtb);
  flash_attn<<<dim3(S_ / 64, B_ * H_), 256, 0, stream>>>(qkv, vtb, aout);
  gemm_bt<0><<<dim3(DM_ / 128, M_ / 128), 256, 0, stream>>>(aout, woutb, out, M_, DM_, DM_);
}

// Round 4
// 345.190 us; speedup vs baseline: 1.5229x; 1.2044x over previous
//
// Fused attention block (QKV proj + RoPE + flash attention + out proj), MI355X gfx950.
// R4: flash_attn restructured: swapped QK^T (mfma(K,Q)) puts each q-row's scores
// lane-local -> in-register softmax (2 shfl_xor instead of 32 per wave-tile); P
// written as packed ds_write_b64 into the verified swizzled lPw layout; 32 q-rows
// per wave (128/block) so kf/vf LDS fragments are reused across two row-groups
// (per-row ds_read_b128 nearly halved) and K/V global re-reads halve.
// Double-buffered K/V staging, log2-domain softmax, defer-max THR=10 retained.
// Workspace layout (needs ~113 MiB):
//   [0,16M)    x_bf16, later reused as attn_out
//   [16,40M)   w_qkv bf16
//   [40,48M)   w_out bf16
//   [48,96M)   qkv   bf16 [4096][6144]
//   [96,112M)  v^T   bf16 [32*128][2048]
//   [112M,..)  cos/sin tables fp32 [2048][64] each

#include <hip/hip_runtime.h>
#include <math.h>
#include <stdint.h>

typedef unsigned short u16;
typedef unsigned int u32;
typedef float f32x4 __attribute__((ext_vector_type(4)));
typedef __bf16 bf16x8 __attribute__((ext_vector_type(8)));

typedef const __attribute__((address_space(1))) u32* gas1;
typedef __attribute__((address_space(3))) u32* las3;

#define B_ 2
#define S_ 2048
#define DM_ 2048
#define H_ 16
#define HD_ 128
#define NO_ 6144
#define M_ 4096

__device__ __forceinline__ u16 f2bf(float f) {
  u32 u = __float_as_uint(f);
  u32 r = (u + 0x7fffu + ((u >> 16) & 1u)) >> 16;  // RNE
  return (u16)r;
}
__device__ __forceinline__ float bf2f(u16 h) {
  return __uint_as_float(((u32)h) << 16);
}

// ---------------------------------------------------------------- convert
__global__ void cvt_bf16(const float* __restrict__ in, u16* __restrict__ out, int n) {
  int i = (blockIdx.x * blockDim.x + threadIdx.x) * 4;
  int stride = gridDim.x * blockDim.x * 4;
  for (; i < n; i += stride) {
    float4 v = *(const float4*)(in + i);
    ushort4 o;
    o.x = f2bf(v.x); o.y = f2bf(v.y); o.z = f2bf(v.z); o.w = f2bf(v.w);
    *(ushort4*)(out + i) = o;
  }
}

// ---------------------------------------------------------------- rope tables
__global__ void rope_tables(float* __restrict__ ct, float* __restrict__ st) {
  int i = blockIdx.x * blockDim.x + threadIdx.x;  // S_*64 threads
  int s = i >> 6, j = i & 63;
  float inv = powf(10000.0f, -(float)j / 64.0f);
  float f = (float)s * inv;
  ct[i] = cosf(f);
  st[i] = sinf(f);
}

// ---------------------------------------------------------------- GEMM  C = A * B^T
// A [M][K] bf16 row-major, B [N][K] bf16 row-major (B^T layout), both K%32==0.
// m97 structure: 128x128 tile, BK=32, 256 thr (4 waves, 2x2), 4x4 16x16x32 frags/wave,
// global_load_lds width 16, 2 barriers per K-step.
template <int OUT_BF16>
__global__ __launch_bounds__(256) void gemm_bt(const u16* __restrict__ A,
                                               const u16* __restrict__ B,
                                               void* __restrict__ Cv,
                                               int M, int N, int K) {
  __shared__ u16 lA[128 * 32];
  __shared__ u16 lB[128 * 32];
  const int t = threadIdx.x;
  const int m0 = blockIdx.y * 128, n0 = blockIdx.x * 128;
  const int w = t >> 6, l = t & 63, lr = l & 15, lg = l >> 4;
  const int wm = (w >> 1) * 64, wn = (w & 1) * 64;
  f32x4 acc[4][4] = {};
  const int srow = t >> 2;       // staging row 0..63 (per round)
  const int scol = (t & 3) * 8;  // staging col chunk
  const u16* Ag = A + (size_t)(m0 + srow) * K + scol;
  const u16* Bg = B + (size_t)(n0 + srow) * K + scol;

  for (int k0 = 0; k0 < K; k0 += 32) {
    __syncthreads();  // previous tile fully consumed
#pragma unroll
    for (int i = 0; i < 2; i++) {
      __builtin_amdgcn_global_load_lds((gas1)(Ag + (size_t)i * 64 * K + k0),
                                       (las3)(lA + (i * 256 + w * 64) * 8), 16, 0, 0);
      __builtin_amdgcn_global_load_lds((gas1)(Bg + (size_t)i * 64 * K + k0),
                                       (las3)(lB + (i * 256 + w * 64) * 8), 16, 0, 0);
    }
    __syncthreads();  // staged tile visible
    bf16x8 af[4], bfr[4];
#pragma unroll
    for (int mi = 0; mi < 4; mi++)
      af[mi] = *(const bf16x8*)&lA[(wm + mi * 16 + lr) * 32 + lg * 8];
#pragma unroll
    for (int ni = 0; ni < 4; ni++)
      bfr[ni] = *(const bf16x8*)&lB[(wn + ni * 16 + lr) * 32 + lg * 8];
#pragma unroll
    for (int mi = 0; mi < 4; mi++)
#pragma unroll
      for (int ni = 0; ni < 4; ni++)
        acc[mi][ni] =
            __builtin_amdgcn_mfma_f32_16x16x32_bf16(af[mi], bfr[ni], acc[mi][ni], 0, 0, 0);
  }

  // epilogue: D row=(lane>>4)*4+j, col=lane&15 (m89/m91-verified layout)
#pragma unroll
  for (int mi = 0; mi < 4; mi++)
#pragma unroll
    for (int ni = 0; ni < 4; ni++) {
      int row = m0 + wm + mi * 16 + lg * 4;
      int col = n0 + wn + ni * 16 + lr;
      if (OUT_BF16) {
        u16* C = (u16*)Cv;
#pragma unroll
        for (int j = 0; j < 4; j++) C[(size_t)(row + j) * N + col] = f2bf(acc[mi][ni][j]);
      } else {
        float* C = (float*)Cv;
#pragma unroll
        for (int j = 0; j < 4; j++) C[(size_t)(row + j) * N + col] = acc[mi][ni][j];
      }
    }
}

// ---------------------------------------------------------------- RoPE in place on q,k
// thread -> (row=b*S+s, hh in [0,32): 0-15 q heads, 16-31 k heads, j in [0,64))
// out[j]    = e1*cos - e2*sin ;  out[j+64] = e2*cos + e1*sin
// q additionally scaled by (1/sqrt(128)) * log2(e)  -> softmax runs in log2 domain.
__global__ void rope_apply(u16* __restrict__ qkv, const float* __restrict__ ct,
                           const float* __restrict__ st) {
  int i = blockIdx.x * blockDim.x + threadIdx.x;  // M_*32*64 threads
  int j = i & 63;
  int hh = (i >> 6) & 31;
  int row = i >> 11;
  int s = row & (S_ - 1);
  int col = (hh < 16) ? hh * 128 : 2048 + (hh - 16) * 128;
  u16* p = qkv + (size_t)row * NO_ + col + j;
  float e1 = bf2f(p[0]), e2 = bf2f(p[64]);
  float c = ct[(s << 6) + j], sn = st[(s << 6) + j];
  float o1 = e1 * c - e2 * sn;
  float o2 = e2 * c + e1 * sn;
  if (hh < 16) {  // fold softmax scale * log2(e) into q
    const float kq = 0.08838834764831845f * 1.4426950408889634f;
    o1 *= kq;
    o2 *= kq;
  }
  p[0] = f2bf(o1);
  p[64] = f2bf(o2);
}

// ---------------------------------------------------------------- V transpose
// qkv[b*S+s][4096 + h*128 + d] -> vt[(b*16+h)*128 + d][s]   (LDS-tiled, swizzled)
__global__ __launch_bounds__(256) void transpose_v(const u16* __restrict__ qkv,
                                                   u16* __restrict__ vt) {
  __shared__ u16 lds[128 * 64];
  const int bh = blockIdx.y;
  const int b = bh >> 4, h = bh & 15;
  const int s0 = blockIdx.x * 64;
  const int t = threadIdx.x;
  union { uint4 v; u16 e[8]; } uu;
#pragma unroll
  for (int i = 0; i < 4; i++) {
    int s = i * 16 + (t >> 4);
    int dc = (t & 15) * 8;
    uu.v = *(const uint4*)(qkv + (size_t)(b * S_ + s0 + s) * NO_ + 4096 + h * 128 + dc);
#pragma unroll
    for (int q = 0; q < 8; q++) {
      int d = dc + q;
      lds[d * 64 + (s ^ (((d >> 3) & 7) << 3))] = uu.e[q];
    }
  }
  __syncthreads();
#pragma unroll
  for (int i = 0; i < 4; i++) {
    int d = i * 32 + (t >> 3);
    int sc = (t & 7) * 8;
    uint4 v = *(const uint4*)&lds[d * 64 + (sc ^ (((d >> 3) & 7) << 3))];
    *(uint4*)(vt + (size_t)(bh * 128 + d) * S_ + s0 + sc) = v;
  }
}

// ---------------------------------------------------------------- flash attention
// grid (S/128, B*H); 256 thr = 4 waves; wave w owns q rows [q0+32w, q0+32w+32)
// as two 16-row groups g=0,1. KV tile = 64, double-buffered staging (as R3).
// SWAPPED QK^T: sc[g][cb] = mfma(kf, qf[g]) -> lane (lr,lg) holds
// S[k = cb*16+lg*4+j][q = g*16+lr]: softmax per-lane over 16 k-vals + 2 shfl_xor
// across the 4 lg-replicas. P packed to bf16 and written as 4x ds_write_b64 into
// the swizzled lPw layout; PV path identical to R3 (verified layouts).
__global__ __launch_bounds__(256, 2) void flash_attn(const u16* __restrict__ qkv,
                                                     const u16* __restrict__ vt,
                                                     u16* __restrict__ ao) {
  __shared__ u16 lK[2][64 * 128];
  __shared__ u16 lV[2][128 * 64];
  __shared__ u16 lP[4][2][16 * 64];
  const int t = threadIdx.x;
  const int w = t >> 6, l = t & 63, lr = l & 15, lg = l >> 4;
  const int bh = blockIdx.y, b = bh >> 4, h = bh & 15;
  const int q0 = blockIdx.x * 128;

  // Q fragments (B operand now): lane holds Q[g*16+lr][c*32 + lg*8 + e]
  bf16x8 qf[2][4];
#pragma unroll
  for (int g = 0; g < 2; g++) {
    const u16* Qg = qkv + (size_t)(b * S_ + q0 + w * 32 + g * 16 + lr) * NO_ + h * 128;
#pragma unroll
    for (int c = 0; c < 4; c++) qf[g][c] = *(const bf16x8*)(Qg + c * 32 + lg * 8);
  }

  f32x4 acc[2][8] = {};
  float m_run[2] = {-INFINITY, -INFINITY};
  float l_run[2] = {0.f, 0.f};

  // ---- staging source pointers (advance one tile per issue). Wave w stages:
  //  K rows  [w*16 + q*4 + (l>>4)],  dest chunk l&15, src chunk = (l&15) ^ (r&15)
  //  V rows  [w*32 + q*8 + (l>>3)],  dest chunk l&7,  src chunk = (l&7) ^ (d&7)
  const u16* ksrc[4];
  const u16* vsrc[4];
#pragma unroll
  for (int q = 0; q < 4; q++) {
    int rt = w * 16 + q * 4 + (l >> 4);            // row within K tile
    int ck = (l & 15) ^ (rt & 15);                 // pre-swizzled source chunk
    ksrc[q] = qkv + (size_t)(b * S_ + rt) * NO_ + 2048 + h * 128 + ck * 8;
    int d = w * 32 + q * 8 + (l >> 3);             // row within V^T tile (d dim)
    int cv = (l & 7) ^ (d & 7);
    vsrc[q] = vt + (size_t)(bh * 128 + d) * S_ + cv * 8;
  }

  // ---- prologue: stage tile 0 into buffer 0
#pragma unroll
  for (int q = 0; q < 4; q++) {
    __builtin_amdgcn_global_load_lds((gas1)ksrc[q],
                                     (las3)(lK[0] + (w * 16 + q * 4) * 128), 16, 0, 0);
    __builtin_amdgcn_global_load_lds((gas1)vsrc[q],
                                     (las3)(lV[0] + (w * 32 + q * 8) * 64), 16, 0, 0);
    ksrc[q] += (size_t)64 * NO_;
    vsrc[q] += 64;
  }
  __syncthreads();  // buffer 0 staged

  const int NT = S_ / 64;
  for (int kt = 0; kt < NT; kt++) {
    const int cur = kt & 1;
    // ---- issue next tile's staging into the other buffer (latency hidden by compute)
    if (kt + 1 < NT) {
#pragma unroll
      for (int q = 0; q < 4; q++) {
        __builtin_amdgcn_global_load_lds((gas1)ksrc[q],
                                         (las3)(lK[cur ^ 1] + (w * 16 + q * 4) * 128), 16, 0, 0);
        __builtin_amdgcn_global_load_lds((gas1)vsrc[q],
                                         (las3)(lV[cur ^ 1] + (w * 32 + q * 8) * 64), 16, 0, 0);
        ksrc[q] += (size_t)64 * NO_;
        vsrc[q] += 64;
      }
    }

    // ---- S^T = K Q^T (log2 domain): lane (lr,lg) reg (cb,j) = S[cb*16+lg*4+j][g*16+lr]
    f32x4 sc[2][4];
#pragma unroll
    for (int g = 0; g < 2; g++)
#pragma unroll
      for (int cb = 0; cb < 4; cb++) sc[g][cb] = (f32x4){0.f, 0.f, 0.f, 0.f};
#pragma unroll
    for (int cb = 0; cb < 4; cb++) {
      int r = cb * 16 + lr;
#pragma unroll
      for (int c = 0; c < 4; c++) {
        bf16x8 kf = *(const bf16x8*)&lK[cur][r * 128 + ((c * 32 + lg * 8) ^ ((r & 15) << 3))];
        sc[0][cb] = __builtin_amdgcn_mfma_f32_16x16x32_bf16(kf, qf[0][c], sc[0][cb], 0, 0, 0);
        sc[1][cb] = __builtin_amdgcn_mfma_f32_16x16x32_bf16(kf, qf[1][c], sc[1][cb], 0, 0, 0);
      }
    }

    // ---- online softmax (log2 domain), in-register per q-row, defer-max
    float tmax[2];
#pragma unroll
    for (int g = 0; g < 2; g++) {
      float v = sc[g][0][0];
#pragma unroll
      for (int cb = 0; cb < 4; cb++)
#pragma unroll
        for (int j = 0; j < 4; j++) v = fmaxf(v, sc[g][cb][j]);
      v = fmaxf(v, __shfl_xor(v, 16));
      v = fmaxf(v, __shfl_xor(v, 32));
      tmax[g] = v;
    }
    bool ok = (tmax[0] <= m_run[0] + 10.0f) && (tmax[1] <= m_run[1] + 10.0f);
    if (!__all(ok)) {
      float resc[2];
#pragma unroll
      for (int g = 0; g < 2; g++) {
        float mn = fmaxf(m_run[g], tmax[g]);
        resc[g] = exp2f(m_run[g] - mn);
        m_run[g] = mn;
        l_run[g] *= resc[g];
      }
#pragma unroll
      for (int g = 0; g < 2; g++)
#pragma unroll
        for (int j = 0; j < 4; j++) {
          float rj = __shfl(resc[g], lg * 4 + j);  // lane lg*4+j has q-row lg*4+j
#pragma unroll
          for (int nb = 0; nb < 8; nb++) acc[g][nb][j] *= rj;
        }
    }
#pragma unroll
    for (int g = 0; g < 2; g++) {
      float ps = 0.f;
#pragma unroll
      for (int cb = 0; cb < 4; cb++)
#pragma unroll
        for (int j = 0; j < 4; j++) {
          float p = exp2f(sc[g][cb][j] - m_run[g]);
          sc[g][cb][j] = p;
          ps += p;
        }
      ps += __shfl_xor(ps, 16);
      ps += __shfl_xor(ps, 32);
      l_run[g] += ps;
    }

    // ---- P -> LDS: lane owns P[q=g*16+lr][k=cb*16+lg*4 .. +4] -> one b64 per (g,cb)
#pragma unroll
    for (int g = 0; g < 2; g++) {
      u16* lPw = lP[w][g];
#pragma unroll
      for (int cb = 0; cb < 4; cb++) {
        ushort4 pk;
        pk.x = f2bf(sc[g][cb][0]);
        pk.y = f2bf(sc[g][cb][1]);
        pk.z = f2bf(sc[g][cb][2]);
        pk.w = f2bf(sc[g][cb][3]);
        *(ushort4*)&lPw[lr * 64 + ((cb * 16 + lg * 4) ^ ((lr & 7) << 3))] = pk;
      }
    }

    // ---- O += P V : A = P[16][64] per group, B = V chunk (from V^T tile)
#pragma unroll
    for (int c2 = 0; c2 < 2; c2++) {
      bf16x8 pf0 = *(const bf16x8*)&lP[w][0][lr * 64 + ((c2 * 32 + lg * 8) ^ ((lr & 7) << 3))];
      bf16x8 pf1 = *(const bf16x8*)&lP[w][1][lr * 64 + ((c2 * 32 + lg * 8) ^ ((lr & 7) << 3))];
#pragma unroll
      for (int nb = 0; nb < 8; nb++) {
        int r = nb * 16 + lr;
        bf16x8 vf = *(const bf16x8*)&lV[cur][r * 64 + ((c2 * 32 + lg * 8) ^ ((r & 7) << 3))];
        acc[0][nb] = __builtin_amdgcn_mfma_f32_16x16x32_bf16(pf0, vf, acc[0][nb], 0, 0, 0);
        acc[1][nb] = __builtin_amdgcn_mfma_f32_16x16x32_bf16(pf1, vf, acc[1][nb], 0, 0, 0);
      }
    }

    __syncthreads();  // drains next-tile staging (covered by compute) + frees cur
  }

  // ---- epilogue: normalize and write attn_out[b*S+q][h*128+d] bf16
#pragma unroll
  for (int g = 0; g < 2; g++) {
    float linv[4];
#pragma unroll
    for (int j = 0; j < 4; j++) linv[j] = 1.0f / __shfl(l_run[g], lg * 4 + j);
#pragma unroll
    for (int nb = 0; nb < 8; nb++)
#pragma unroll
      for (int j = 0; j < 4; j++) {
        int qrow = q0 + w * 32 + g * 16 + lg * 4 + j;
        ao[(size_t)(b * S_ + qrow) * 2048 + h * 128 + nb * 16 + lr] =
            f2bf(acc[g][nb][j] * linv[j]);
      }
  }
}

// ---------------------------------------------------------------- launch
extern "C" void kernel_launch(void* const* d_in, const int* in_sizes, int n_in,
                              void* d_out, int out_size, void* d_ws, size_t ws_size,
                              hipStream_t stream) {
  const float* x = (const float*)d_in[0];
  const float* wqkv = (const float*)d_in[1];
  const float* wout = (const float*)d_in[2];
  float* out = (float*)d_out;

  char* ws = (char*)d_ws;
  u16* xbf = (u16*)(ws);                              // 16 MiB (reused as attn_out)
  u16* wqkvb = (u16*)(ws + ((size_t)16 << 20));       // 24 MiB
  u16* woutb = (u16*)(ws + ((size_t)40 << 20));       // 8 MiB
  u16* qkv = (u16*)(ws + ((size_t)48 << 20));         // 48 MiB
  u16* vtb = (u16*)(ws + ((size_t)96 << 20));         // 16 MiB
  float* ct = (float*)(ws + ((size_t)112 << 20));     // 0.5 MiB
  float* st = (float*)(ws + ((size_t)112 << 20) + ((size_t)1 << 19));
  u16* aout = xbf;  // x_bf16 dead after gemm_qkv

  cvt_bf16<<<4096, 256, 0, stream>>>(x, xbf, M_ * DM_);
  cvt_bf16<<<4096, 256, 0, stream>>>(wqkv, wqkvb, NO_ * DM_);
  cvt_bf16<<<4096, 256, 0, stream>>>(wout, woutb, DM_ * DM_);
  rope_tables<<<(S_ * 64) / 256, 256, 0, stream>>>(ct, st);
  gemm_bt<1><<<dim3(NO_ / 128, M_ / 128), 256, 0, stream>>>(xbf, wqkvb, qkv, M_, NO_, DM_);
  rope_apply<<<(M_ * 32 * 64) / 256, 256, 0, stream>>>(qkv, ct, st);
  transpose_v<<<dim3(S_ / 64, B_ * H_), 256, 0, stream>>>(qkv, vtb);
  flash_attn<<<dim3(S_ / 128, B_ * H_), 256, 0, stream>>>(qkv, vtb, aout);
  gemm_bt<0><<<dim3(DM_ / 128, M_ / 128), 256, 0, stream>>>(aout, woutb, out, M_, DM_, DM_);
}

// Round 5
// 337.687 us; speedup vs baseline: 1.5568x; 1.0222x over previous
//
// Fused attention block (QKV proj + RoPE + flash attention + out proj), MI355X gfx950.
// R5: qkv GEMM moved to the 256x256 8-phase counted-vmcnt schedule (T3+T4+T5):
// 512 thr / 8 waves (2Mx4N), BK=64 split in two K-halves, LDS 128 KiB
// [2 buf][A,B][2 khalf][256x32] (64B row stride -> bank-uniform, no swizzle),
// per phase {ds_read subtile | 2x global_load_lds (1 half-tile)} -> s_barrier ->
// lgkmcnt(0) -> setprio(1) 16 MFMA setprio(0) -> s_barrier; vmcnt(6) ONLY at
// phases 4 and 8 (3 half-tiles in flight, never drained to 0 in the loop).
// Slot-reuse and wait coverage derived and checked phase-by-phase; end-of-K
// staging clamped to the last tile (re-stages identical bytes -> race-free).
// flash_attn: + T5 setprio around QK^T and PV MFMA clusters.
// Workspace layout (needs ~113 MiB): see R4.

#include <hip/hip_runtime.h>
#include <math.h>
#include <stdint.h>

typedef unsigned short u16;
typedef unsigned int u32;
typedef float f32x4 __attribute__((ext_vector_type(4)));
typedef __bf16 bf16x8 __attribute__((ext_vector_type(8)));

typedef const __attribute__((address_space(1))) u32* gas1;
typedef __attribute__((address_space(3))) u32* las3;

#define B_ 2
#define S_ 2048
#define DM_ 2048
#define H_ 16
#define HD_ 128
#define NO_ 6144
#define M_ 4096

__device__ __forceinline__ u16 f2bf(float f) {
  u32 u = __float_as_uint(f);
  u32 r = (u + 0x7fffu + ((u >> 16) & 1u)) >> 16;  // RNE
  return (u16)r;
}
__device__ __forceinline__ float bf2f(u16 h) {
  return __uint_as_float(((u32)h) << 16);
}

// ---------------------------------------------------------------- convert
__global__ void cvt_bf16(const float* __restrict__ in, u16* __restrict__ out, int n) {
  int i = (blockIdx.x * blockDim.x + threadIdx.x) * 4;
  int stride = gridDim.x * blockDim.x * 4;
  for (; i < n; i += stride) {
    float4 v = *(const float4*)(in + i);
    ushort4 o;
    o.x = f2bf(v.x); o.y = f2bf(v.y); o.z = f2bf(v.z); o.w = f2bf(v.w);
    *(ushort4*)(out + i) = o;
  }
}

// ---------------------------------------------------------------- rope tables
__global__ void rope_tables(float* __restrict__ ct, float* __restrict__ st) {
  int i = blockIdx.x * blockDim.x + threadIdx.x;  // S_*64 threads
  int s = i >> 6, j = i & 63;
  float inv = powf(10000.0f, -(float)j / 64.0f);
  float f = (float)s * inv;
  ct[i] = cosf(f);
  st[i] = sinf(f);
}

// ---------------------------------------------------------------- GEMM 256^2 8-phase
// C = A * B^T, A [M][K], B [N][K] bf16 row-major, C bf16. M,N %256==0, K %128==0.
// 8 waves: wm = w>>2 (2), wn = w&3 (4); per-wave C = 128x64 = acc[8][4] 16x16 frags.
// LDS: [buf][op A/B][khalf][256 rows][32 cols] bf16; staged half-tile = one
// (op,khalf) = 16 KB = 2 global_load_lds per thread. No swizzle (64B row stride
// is bank-uniform for the frag read pattern).
__global__ __launch_bounds__(512, 2) void gemm8_bt(const u16* __restrict__ A,
                                                   const u16* __restrict__ B,
                                                   u16* __restrict__ C,
                                                   int M, int N, int K) {
  __shared__ u16 lds8[2][2][2][8192];
  const int t = threadIdx.x;
  const int w = t >> 6, l = t & 63, lr = l & 15, lg = l >> 4;
  const int wm = w >> 2, wn = w & 3;
  const int m0 = blockIdx.y * 256, n0 = blockIdx.x * 256;
  const int r0 = t >> 2, c = t & 3;
  const u16* pA0 = A + (size_t)(m0 + r0) * K + c * 8;
  const u16* pB0 = B + (size_t)(n0 + r0) * K + c * 8;
  const size_t j1 = (size_t)128 * K;

  f32x4 acc[8][4] = {};
  bf16x8 af[8], bq[4];

  const int NT = K / 64, NI = NT / 2;

#define STG(T_, kh_, op_, buf_)                                                      \
  do {                                                                               \
    const u16* s_ = (op_ ? pB0 : pA0) + (T_) * 64 + (kh_) * 32;                      \
    u16* d_ = &lds8[buf_][op_][kh_][0] + w * 512;                                    \
    __builtin_amdgcn_global_load_lds((gas1)s_, (las3)d_, 16, 0, 0);                  \
    __builtin_amdgcn_global_load_lds((gas1)(s_ + j1), (las3)(d_ + 4096), 16, 0, 0);  \
  } while (0)

#define LDF(buf_, kh_)                                                         \
  do {                                                                         \
    const u16* a_ = &lds8[buf_][0][kh_][0];                                    \
    const u16* b_ = &lds8[buf_][1][kh_][0];                                    \
    _Pragma("unroll") for (int mi = 0; mi < 8; ++mi)                           \
        af[mi] = *(const bf16x8*)&a_[(wm * 128 + mi * 16 + lr) * 32 + lg * 8]; \
    _Pragma("unroll") for (int ni = 0; ni < 4; ++ni)                           \
        bq[ni] = *(const bf16x8*)&b_[(wn * 64 + ni * 16 + lr) * 32 + lg * 8];  \
  } while (0)

#define MFH(h_)                                                                \
  do {                                                                         \
    __builtin_amdgcn_s_setprio(1);                                             \
    _Pragma("unroll") for (int mi = 0; mi < 4; ++mi)                           \
        _Pragma("unroll") for (int ni = 0; ni < 4; ++ni)                       \
            acc[(h_) * 4 + mi][ni] = __builtin_amdgcn_mfma_f32_16x16x32_bf16(  \
                af[(h_) * 4 + mi], bq[ni], acc[(h_) * 4 + mi][ni], 0, 0, 0);   \
    __builtin_amdgcn_s_setprio(0);                                             \
  } while (0)

#define BAR() __builtin_amdgcn_s_barrier()
#define LGKM0() asm volatile("s_waitcnt lgkmcnt(0)" ::: "memory")
#define VM6() asm volatile("s_waitcnt vmcnt(6)" ::: "memory")

  // ---- prologue: tile0 {A0,B0,A1,B1} -> buf0; tile1 {A0,B0,A1} -> buf1 (14 loads)
  STG(0, 0, 0, 0); STG(0, 0, 1, 0); STG(0, 1, 0, 0); STG(0, 1, 1, 0);
  STG(1, 0, 0, 1); STG(1, 0, 1, 1); STG(1, 1, 0, 1);
  VM6();  // tile0 fully landed (6 outstanding = tile1's 3 halves)
  BAR();

  for (int i = 0; i < NI; ++i) {
    const int T = 2 * i;
    const int Tp2 = (T + 2 < NT) ? T + 2 : NT - 1;
    const int Tp3 = (T + 3 < NT) ? T + 3 : NT - 1;
    // ph1: read buf0.kh0; stage (T+1).B1 -> buf1 (completes tile T+1)
    LDF(0, 0);
    STG(T + 1, 1, 1, 1);
    BAR(); LGKM0(); MFH(0); BAR();
    // ph2: stage (T+2).A0 -> buf0 (slot free since ph1 drained)
    STG(Tp2, 0, 0, 0);
    BAR(); MFH(1); BAR();
    // ph3: read buf0.kh1; stage (T+2).B0
    LDF(0, 1);
    STG(Tp2, 0, 1, 0);
    BAR(); LGKM0(); MFH(0); BAR();
    // ph4: stage (T+2).A1; WAIT vmcnt(6) -> tile T+1 all landed
    STG(Tp2, 1, 0, 0);
    VM6(); BAR(); MFH(1); BAR();
    // ph5: read buf1.kh0 (tile T+1); stage (T+2).B1
    LDF(1, 0);
    STG(Tp2, 1, 1, 0);
    BAR(); LGKM0(); MFH(0); BAR();
    // ph6: stage (T+3).A0 -> buf1
    STG(Tp3, 0, 0, 1);
    BAR(); MFH(1); BAR();
    // ph7: read buf1.kh1; stage (T+3).B0
    LDF(1, 1);
    STG(Tp3, 0, 1, 1);
    BAR(); LGKM0(); MFH(0); BAR();
    // ph8: stage (T+3).A1; WAIT vmcnt(6) -> tile T+2 all landed
    STG(Tp3, 1, 0, 1);
    VM6(); BAR(); MFH(1); BAR();
  }
  asm volatile("s_waitcnt vmcnt(0)" ::: "memory");
  BAR();

  // ---- epilogue: D row=(lane>>4)*4+j (M dim), col=lane&15 (N dim)
#pragma unroll
  for (int mi = 0; mi < 8; ++mi)
#pragma unroll
    for (int ni = 0; ni < 4; ++ni) {
      int row = m0 + wm * 128 + mi * 16 + lg * 4;
      int col = n0 + wn * 64 + ni * 16 + lr;
#pragma unroll
      for (int j = 0; j < 4; ++j)
        C[(size_t)(row + j) * N + col] = f2bf(acc[mi][ni][j]);
    }
#undef STG
#undef LDF
#undef MFH
#undef BAR
#undef LGKM0
#undef VM6
}

// ---------------------------------------------------------------- GEMM  C = A * B^T
// m97 structure (kept for the out-projection: N=2048 -> 512 blocks at 128^2).
template <int OUT_BF16>
__global__ __launch_bounds__(256) void gemm_bt(const u16* __restrict__ A,
                                               const u16* __restrict__ B,
                                               void* __restrict__ Cv,
                                               int M, int N, int K) {
  __shared__ u16 lA[128 * 32];
  __shared__ u16 lB[128 * 32];
  const int t = threadIdx.x;
  const int m0 = blockIdx.y * 128, n0 = blockIdx.x * 128;
  const int w = t >> 6, l = t & 63, lr = l & 15, lg = l >> 4;
  const int wm = (w >> 1) * 64, wn = (w & 1) * 64;
  f32x4 acc[4][4] = {};
  const int srow = t >> 2;       // staging row 0..63 (per round)
  const int scol = (t & 3) * 8;  // staging col chunk
  const u16* Ag = A + (size_t)(m0 + srow) * K + scol;
  const u16* Bg = B + (size_t)(n0 + srow) * K + scol;

  for (int k0 = 0; k0 < K; k0 += 32) {
    __syncthreads();  // previous tile fully consumed
#pragma unroll
    for (int i = 0; i < 2; i++) {
      __builtin_amdgcn_global_load_lds((gas1)(Ag + (size_t)i * 64 * K + k0),
                                       (las3)(lA + (i * 256 + w * 64) * 8), 16, 0, 0);
      __builtin_amdgcn_global_load_lds((gas1)(Bg + (size_t)i * 64 * K + k0),
                                       (las3)(lB + (i * 256 + w * 64) * 8), 16, 0, 0);
    }
    __syncthreads();  // staged tile visible
    bf16x8 af[4], bfr[4];
#pragma unroll
    for (int mi = 0; mi < 4; mi++)
      af[mi] = *(const bf16x8*)&lA[(wm + mi * 16 + lr) * 32 + lg * 8];
#pragma unroll
    for (int ni = 0; ni < 4; ni++)
      bfr[ni] = *(const bf16x8*)&lB[(wn + ni * 16 + lr) * 32 + lg * 8];
#pragma unroll
    for (int mi = 0; mi < 4; mi++)
#pragma unroll
      for (int ni = 0; ni < 4; ni++)
        acc[mi][ni] =
            __builtin_amdgcn_mfma_f32_16x16x32_bf16(af[mi], bfr[ni], acc[mi][ni], 0, 0, 0);
  }

  // epilogue: D row=(lane>>4)*4+j, col=lane&15 (m89/m91-verified layout)
#pragma unroll
  for (int mi = 0; mi < 4; mi++)
#pragma unroll
    for (int ni = 0; ni < 4; ni++) {
      int row = m0 + wm + mi * 16 + lg * 4;
      int col = n0 + wn + ni * 16 + lr;
      if (OUT_BF16) {
        u16* C = (u16*)Cv;
#pragma unroll
        for (int j = 0; j < 4; j++) C[(size_t)(row + j) * N + col] = f2bf(acc[mi][ni][j]);
      } else {
        float* C = (float*)Cv;
#pragma unroll
        for (int j = 0; j < 4; j++) C[(size_t)(row + j) * N + col] = acc[mi][ni][j];
      }
    }
}

// ---------------------------------------------------------------- RoPE in place on q,k
// q additionally scaled by (1/sqrt(128)) * log2(e)  -> softmax runs in log2 domain.
__global__ void rope_apply(u16* __restrict__ qkv, const float* __restrict__ ct,
                           const float* __restrict__ st) {
  int i = blockIdx.x * blockDim.x + threadIdx.x;  // M_*32*64 threads
  int j = i & 63;
  int hh = (i >> 6) & 31;
  int row = i >> 11;
  int s = row & (S_ - 1);
  int col = (hh < 16) ? hh * 128 : 2048 + (hh - 16) * 128;
  u16* p = qkv + (size_t)row * NO_ + col + j;
  float e1 = bf2f(p[0]), e2 = bf2f(p[64]);
  float c = ct[(s << 6) + j], sn = st[(s << 6) + j];
  float o1 = e1 * c - e2 * sn;
  float o2 = e2 * c + e1 * sn;
  if (hh < 16) {  // fold softmax scale * log2(e) into q
    const float kq = 0.08838834764831845f * 1.4426950408889634f;
    o1 *= kq;
    o2 *= kq;
  }
  p[0] = f2bf(o1);
  p[64] = f2bf(o2);
}

// ---------------------------------------------------------------- V transpose
// qkv[b*S+s][4096 + h*128 + d] -> vt[(b*16+h)*128 + d][s]   (LDS-tiled, swizzled)
__global__ __launch_bounds__(256) void transpose_v(const u16* __restrict__ qkv,
                                                   u16* __restrict__ vt) {
  __shared__ u16 lds[128 * 64];
  const int bh = blockIdx.y;
  const int b = bh >> 4, h = bh & 15;
  const int s0 = blockIdx.x * 64;
  const int t = threadIdx.x;
  union { uint4 v; u16 e[8]; } uu;
#pragma unroll
  for (int i = 0; i < 4; i++) {
    int s = i * 16 + (t >> 4);
    int dc = (t & 15) * 8;
    uu.v = *(const uint4*)(qkv + (size_t)(b * S_ + s0 + s) * NO_ + 4096 + h * 128 + dc);
#pragma unroll
    for (int q = 0; q < 8; q++) {
      int d = dc + q;
      lds[d * 64 + (s ^ (((d >> 3) & 7) << 3))] = uu.e[q];
    }
  }
  __syncthreads();
#pragma unroll
  for (int i = 0; i < 4; i++) {
    int d = i * 32 + (t >> 3);
    int sc = (t & 7) * 8;
    uint4 v = *(const uint4*)&lds[d * 64 + (sc ^ (((d >> 3) & 7) << 3))];
    *(uint4*)(vt + (size_t)(bh * 128 + d) * S_ + s0 + sc) = v;
  }
}

// ---------------------------------------------------------------- flash attention
// grid (S/128, B*H); 256 thr = 4 waves; wave w owns q rows [q0+32w, q0+32w+32)
// as two 16-row groups g=0,1. Swapped QK^T, in-register log2 softmax, defer-max,
// double-buffered K/V staging, T5 setprio around MFMA clusters.
__global__ __launch_bounds__(256, 2) void flash_attn(const u16* __restrict__ qkv,
                                                     const u16* __restrict__ vt,
                                                     u16* __restrict__ ao) {
  __shared__ u16 lK[2][64 * 128];
  __shared__ u16 lV[2][128 * 64];
  __shared__ u16 lP[4][2][16 * 64];
  const int t = threadIdx.x;
  const int w = t >> 6, l = t & 63, lr = l & 15, lg = l >> 4;
  const int bh = blockIdx.y, b = bh >> 4, h = bh & 15;
  const int q0 = blockIdx.x * 128;

  // Q fragments (B operand now): lane holds Q[g*16+lr][c*32 + lg*8 + e]
  bf16x8 qf[2][4];
#pragma unroll
  for (int g = 0; g < 2; g++) {
    const u16* Qg = qkv + (size_t)(b * S_ + q0 + w * 32 + g * 16 + lr) * NO_ + h * 128;
#pragma unroll
    for (int c = 0; c < 4; c++) qf[g][c] = *(const bf16x8*)(Qg + c * 32 + lg * 8);
  }

  f32x4 acc[2][8] = {};
  float m_run[2] = {-INFINITY, -INFINITY};
  float l_run[2] = {0.f, 0.f};

  const u16* ksrc[4];
  const u16* vsrc[4];
#pragma unroll
  for (int q = 0; q < 4; q++) {
    int rt = w * 16 + q * 4 + (l >> 4);            // row within K tile
    int ck = (l & 15) ^ (rt & 15);                 // pre-swizzled source chunk
    ksrc[q] = qkv + (size_t)(b * S_ + rt) * NO_ + 2048 + h * 128 + ck * 8;
    int d = w * 32 + q * 8 + (l >> 3);             // row within V^T tile (d dim)
    int cv = (l & 7) ^ (d & 7);
    vsrc[q] = vt + (size_t)(bh * 128 + d) * S_ + cv * 8;
  }

  // ---- prologue: stage tile 0 into buffer 0
#pragma unroll
  for (int q = 0; q < 4; q++) {
    __builtin_amdgcn_global_load_lds((gas1)ksrc[q],
                                     (las3)(lK[0] + (w * 16 + q * 4) * 128), 16, 0, 0);
    __builtin_amdgcn_global_load_lds((gas1)vsrc[q],
                                     (las3)(lV[0] + (w * 32 + q * 8) * 64), 16, 0, 0);
    ksrc[q] += (size_t)64 * NO_;
    vsrc[q] += 64;
  }
  __syncthreads();  // buffer 0 staged

  const int NT = S_ / 64;
  for (int kt = 0; kt < NT; kt++) {
    const int cur = kt & 1;
    if (kt + 1 < NT) {
#pragma unroll
      for (int q = 0; q < 4; q++) {
        __builtin_amdgcn_global_load_lds((gas1)ksrc[q],
                                         (las3)(lK[cur ^ 1] + (w * 16 + q * 4) * 128), 16, 0, 0);
        __builtin_amdgcn_global_load_lds((gas1)vsrc[q],
                                         (las3)(lV[cur ^ 1] + (w * 32 + q * 8) * 64), 16, 0, 0);
        ksrc[q] += (size_t)64 * NO_;
        vsrc[q] += 64;
      }
    }

    // ---- S^T = K Q^T (log2 domain): lane (lr,lg) reg (cb,j) = S[cb*16+lg*4+j][g*16+lr]
    f32x4 sc[2][4];
#pragma unroll
    for (int g = 0; g < 2; g++)
#pragma unroll
      for (int cb = 0; cb < 4; cb++) sc[g][cb] = (f32x4){0.f, 0.f, 0.f, 0.f};
    __builtin_amdgcn_s_setprio(1);
#pragma unroll
    for (int cb = 0; cb < 4; cb++) {
      int r = cb * 16 + lr;
#pragma unroll
      for (int c = 0; c < 4; c++) {
        bf16x8 kf = *(const bf16x8*)&lK[cur][r * 128 + ((c * 32 + lg * 8) ^ ((r & 15) << 3))];
        sc[0][cb] = __builtin_amdgcn_mfma_f32_16x16x32_bf16(kf, qf[0][c], sc[0][cb], 0, 0, 0);
        sc[1][cb] = __builtin_amdgcn_mfma_f32_16x16x32_bf16(kf, qf[1][c], sc[1][cb], 0, 0, 0);
      }
    }
    __builtin_amdgcn_s_setprio(0);

    // ---- online softmax (log2 domain), in-register per q-row, defer-max
    float tmax[2];
#pragma unroll
    for (int g = 0; g < 2; g++) {
      float v = sc[g][0][0];
#pragma unroll
      for (int cb = 0; cb < 4; cb++)
#pragma unroll
        for (int j = 0; j < 4; j++) v = fmaxf(v, sc[g][cb][j]);
      v = fmaxf(v, __shfl_xor(v, 16));
      v = fmaxf(v, __shfl_xor(v, 32));
      tmax[g] = v;
    }
    bool ok = (tmax[0] <= m_run[0] + 10.0f) && (tmax[1] <= m_run[1] + 10.0f);
    if (!__all(ok)) {
      float resc[2];
#pragma unroll
      for (int g = 0; g < 2; g++) {
        float mn = fmaxf(m_run[g], tmax[g]);
        resc[g] = exp2f(m_run[g] - mn);
        m_run[g] = mn;
        l_run[g] *= resc[g];
      }
#pragma unroll
      for (int g = 0; g < 2; g++)
#pragma unroll
        for (int j = 0; j < 4; j++) {
          float rj = __shfl(resc[g], lg * 4 + j);  // lane lg*4+j has q-row lg*4+j
#pragma unroll
          for (int nb = 0; nb < 8; nb++) acc[g][nb][j] *= rj;
        }
    }
#pragma unroll
    for (int g = 0; g < 2; g++) {
      float ps = 0.f;
#pragma unroll
      for (int cb = 0; cb < 4; cb++)
#pragma unroll
        for (int j = 0; j < 4; j++) {
          float p = exp2f(sc[g][cb][j] - m_run[g]);
          sc[g][cb][j] = p;
          ps += p;
        }
      ps += __shfl_xor(ps, 16);
      ps += __shfl_xor(ps, 32);
      l_run[g] += ps;
    }

    // ---- P -> LDS: lane owns P[q=g*16+lr][k=cb*16+lg*4 .. +4] -> one b64 per (g,cb)
#pragma unroll
    for (int g = 0; g < 2; g++) {
      u16* lPw = lP[w][g];
#pragma unroll
      for (int cb = 0; cb < 4; cb++) {
        ushort4 pk;
        pk.x = f2bf(sc[g][cb][0]);
        pk.y = f2bf(sc[g][cb][1]);
        pk.z = f2bf(sc[g][cb][2]);
        pk.w = f2bf(sc[g][cb][3]);
        *(ushort4*)&lPw[lr * 64 + ((cb * 16 + lg * 4) ^ ((lr & 7) << 3))] = pk;
      }
    }

    // ---- O += P V : A = P[16][64] per group, B = V chunk (from V^T tile)
    __builtin_amdgcn_s_setprio(1);
#pragma unroll
    for (int c2 = 0; c2 < 2; c2++) {
      bf16x8 pf0 = *(const bf16x8*)&lP[w][0][lr * 64 + ((c2 * 32 + lg * 8) ^ ((lr & 7) << 3))];
      bf16x8 pf1 = *(const bf16x8*)&lP[w][1][lr * 64 + ((c2 * 32 + lg * 8) ^ ((lr & 7) << 3))];
#pragma unroll
      for (int nb = 0; nb < 8; nb++) {
        int r = nb * 16 + lr;
        bf16x8 vf = *(const bf16x8*)&lV[cur][r * 64 + ((c2 * 32 + lg * 8) ^ ((r & 7) << 3))];
        acc[0][nb] = __builtin_amdgcn_mfma_f32_16x16x32_bf16(pf0, vf, acc[0][nb], 0, 0, 0);
        acc[1][nb] = __builtin_amdgcn_mfma_f32_16x16x32_bf16(pf1, vf, acc[1][nb], 0, 0, 0);
      }
    }
    __builtin_amdgcn_s_setprio(0);

    __syncthreads();  // drains next-tile staging (covered by compute) + frees cur
  }

  // ---- epilogue: normalize and write attn_out[b*S+q][h*128+d] bf16
#pragma unroll
  for (int g = 0; g < 2; g++) {
    float linv[4];
#pragma unroll
    for (int j = 0; j < 4; j++) linv[j] = 1.0f / __shfl(l_run[g], lg * 4 + j);
#pragma unroll
    for (int nb = 0; nb < 8; nb++)
#pragma unroll
      for (int j = 0; j < 4; j++) {
        int qrow = q0 + w * 32 + g * 16 + lg * 4 + j;
        ao[(size_t)(b * S_ + qrow) * 2048 + h * 128 + nb * 16 + lr] =
            f2bf(acc[g][nb][j] * linv[j]);
      }
  }
}

// ---------------------------------------------------------------- launch
extern "C" void kernel_launch(void* const* d_in, const int* in_sizes, int n_in,
                              void* d_out, int out_size, void* d_ws, size_t ws_size,
                              hipStream_t stream) {
  const float* x = (const float*)d_in[0];
  const float* wqkv = (const float*)d_in[1];
  const float* wout = (const float*)d_in[2];
  float* out = (float*)d_out;

  char* ws = (char*)d_ws;
  u16* xbf = (u16*)(ws);                              // 16 MiB (reused as attn_out)
  u16* wqkvb = (u16*)(ws + ((size_t)16 << 20));       // 24 MiB
  u16* woutb = (u16*)(ws + ((size_t)40 << 20));       // 8 MiB
  u16* qkv = (u16*)(ws + ((size_t)48 << 20));         // 48 MiB
  u16* vtb = (u16*)(ws + ((size_t)96 << 20));         // 16 MiB
  float* ct = (float*)(ws + ((size_t)112 << 20));     // 0.5 MiB
  float* st = (float*)(ws + ((size_t)112 << 20) + ((size_t)1 << 19));
  u16* aout = xbf;  // x_bf16 dead after gemm_qkv

  cvt_bf16<<<4096, 256, 0, stream>>>(x, xbf, M_ * DM_);
  cvt_bf16<<<4096, 256, 0, stream>>>(wqkv, wqkvb, NO_ * DM_);
  cvt_bf16<<<4096, 256, 0, stream>>>(wout, woutb, DM_ * DM_);
  rope_tables<<<(S_ * 64) / 256, 256, 0, stream>>>(ct, st);
  gemm8_bt<<<dim3(NO_ / 256, M_ / 256), 512, 0, stream>>>(xbf, wqkvb, qkv, M_, NO_, DM_);
  rope_apply<<<(M_ * 32 * 64) / 256, 256, 0, stream>>>(qkv, ct, st);
  transpose_v<<<dim3(S_ / 64, B_ * H_), 256, 0, stream>>>(qkv, vtb);
  flash_attn<<<dim3(S_ / 128, B_ * H_), 256, 0, stream>>>(qkv, vtb, aout);
  gemm_bt<0><<<dim3(DM_ / 128, M_ / 128), 256, 0, stream>>>(aout, woutb, out, M_, DM_, DM_);
}

// Round 6
// 332.855 us; speedup vs baseline: 1.5794x; 1.0145x over previous
//
// Fused attention block (QKV proj + RoPE + flash attention + out proj), MI355X gfx950.
// R6: T2 bank-conflict fix for both GEMMs. The [*][32] u16 LDS layout (64B rows)
// gave 8-way conflicts on ds_read_b128 (slot=(row*4+chunk)%8: 16 lr-lanes -> 2
// slots). Fix: chunk' = chunk ^ ((row>>1)&3) -> 2 lanes/slot (free, m136).
// Applied rule-21 style: linear global_load_lds dest + inverse-swizzled SOURCE
// chunk (c' = (t&3)^((t>>3)&3), same for both half-tile sub-loads) + swizzled
// read (lg ^ ((lr>>1)&3)). Same fix in the 128^2 out-proj gemm_bt.
// Workspace layout (needs ~113 MiB): see R4.

#include <hip/hip_runtime.h>
#include <math.h>
#include <stdint.h>

typedef unsigned short u16;
typedef unsigned int u32;
typedef float f32x4 __attribute__((ext_vector_type(4)));
typedef __bf16 bf16x8 __attribute__((ext_vector_type(8)));

typedef const __attribute__((address_space(1))) u32* gas1;
typedef __attribute__((address_space(3))) u32* las3;

#define B_ 2
#define S_ 2048
#define DM_ 2048
#define H_ 16
#define HD_ 128
#define NO_ 6144
#define M_ 4096

__device__ __forceinline__ u16 f2bf(float f) {
  u32 u = __float_as_uint(f);
  u32 r = (u + 0x7fffu + ((u >> 16) & 1u)) >> 16;  // RNE
  return (u16)r;
}
__device__ __forceinline__ float bf2f(u16 h) {
  return __uint_as_float(((u32)h) << 16);
}

// ---------------------------------------------------------------- convert
__global__ void cvt_bf16(const float* __restrict__ in, u16* __restrict__ out, int n) {
  int i = (blockIdx.x * blockDim.x + threadIdx.x) * 4;
  int stride = gridDim.x * blockDim.x * 4;
  for (; i < n; i += stride) {
    float4 v = *(const float4*)(in + i);
    ushort4 o;
    o.x = f2bf(v.x); o.y = f2bf(v.y); o.z = f2bf(v.z); o.w = f2bf(v.w);
    *(ushort4*)(out + i) = o;
  }
}

// ---------------------------------------------------------------- rope tables
__global__ void rope_tables(float* __restrict__ ct, float* __restrict__ st) {
  int i = blockIdx.x * blockDim.x + threadIdx.x;  // S_*64 threads
  int s = i >> 6, j = i & 63;
  float inv = powf(10000.0f, -(float)j / 64.0f);
  float f = (float)s * inv;
  ct[i] = cosf(f);
  st[i] = sinf(f);
}

// ---------------------------------------------------------------- GEMM 256^2 8-phase
// C = A * B^T, A [M][K], B [N][K] bf16 row-major, C bf16. M,N %256==0, K %128==0.
// 8 waves: wm = w>>2 (2), wn = w&3 (4); per-wave C = 128x64 = acc[8][4] 16x16 frags.
// LDS: [buf][op A/B][khalf][256 rows][32 cols] bf16. T2 chunk swizzle:
// LDS[row][chunk^((row>>1)&3)] holds global [row][chunk] (16B chunks 0..3).
__global__ __launch_bounds__(512, 2) void gemm8_bt(const u16* __restrict__ A,
                                                   const u16* __restrict__ B,
                                                   u16* __restrict__ C,
                                                   int M, int N, int K) {
  __shared__ u16 lds8[2][2][2][8192];
  const int t = threadIdx.x;
  const int w = t >> 6, l = t & 63, lr = l & 15, lg = l >> 4;
  const int wm = w >> 2, wn = w & 3;
  const int m0 = blockIdx.y * 256, n0 = blockIdx.x * 256;
  const int r0 = t >> 2;
  const int c = (t & 3) ^ ((t >> 3) & 3);  // inverse-swizzled source chunk
  const int swr = (lr >> 1) & 3;           // read-side swizzle term
  const u16* pA0 = A + (size_t)(m0 + r0) * K + c * 8;
  const u16* pB0 = B + (size_t)(n0 + r0) * K + c * 8;
  const size_t j1 = (size_t)128 * K;

  f32x4 acc[8][4] = {};
  bf16x8 af[8], bq[4];

  const int NT = K / 64, NI = NT / 2;

#define STG(T_, kh_, op_, buf_)                                                      \
  do {                                                                               \
    const u16* s_ = (op_ ? pB0 : pA0) + (T_) * 64 + (kh_) * 32;                      \
    u16* d_ = &lds8[buf_][op_][kh_][0] + w * 512;                                    \
    __builtin_amdgcn_global_load_lds((gas1)s_, (las3)d_, 16, 0, 0);                  \
    __builtin_amdgcn_global_load_lds((gas1)(s_ + j1), (las3)(d_ + 4096), 16, 0, 0);  \
  } while (0)

#define LDF(buf_, kh_)                                                            \
  do {                                                                            \
    const u16* a_ = &lds8[buf_][0][kh_][0];                                       \
    const u16* b_ = &lds8[buf_][1][kh_][0];                                       \
    _Pragma("unroll") for (int mi = 0; mi < 8; ++mi)                              \
        af[mi] = *(const bf16x8*)&a_[(wm * 128 + mi * 16 + lr) * 32 +             \
                                     ((lg ^ swr) * 8)];                           \
    _Pragma("unroll") for (int ni = 0; ni < 4; ++ni)                              \
        bq[ni] = *(const bf16x8*)&b_[(wn * 64 + ni * 16 + lr) * 32 +              \
                                     ((lg ^ swr) * 8)];                           \
  } while (0)

#define MFH(h_)                                                                \
  do {                                                                         \
    __builtin_amdgcn_s_setprio(1);                                             \
    _Pragma("unroll") for (int mi = 0; mi < 4; ++mi)                           \
        _Pragma("unroll") for (int ni = 0; ni < 4; ++ni)                       \
            acc[(h_) * 4 + mi][ni] = __builtin_amdgcn_mfma_f32_16x16x32_bf16(  \
                af[(h_) * 4 + mi], bq[ni], acc[(h_) * 4 + mi][ni], 0, 0, 0);   \
    __builtin_amdgcn_s_setprio(0);                                             \
  } while (0)

#define BAR() __builtin_amdgcn_s_barrier()
#define LGKM0() asm volatile("s_waitcnt lgkmcnt(0)" ::: "memory")
#define VM6() asm volatile("s_waitcnt vmcnt(6)" ::: "memory")

  // ---- prologue: tile0 {A0,B0,A1,B1} -> buf0; tile1 {A0,B0,A1} -> buf1 (14 loads)
  STG(0, 0, 0, 0); STG(0, 0, 1, 0); STG(0, 1, 0, 0); STG(0, 1, 1, 0);
  STG(1, 0, 0, 1); STG(1, 0, 1, 1); STG(1, 1, 0, 1);
  VM6();  // tile0 fully landed (6 outstanding = tile1's 3 halves)
  BAR();

  for (int i = 0; i < NI; ++i) {
    const int T = 2 * i;
    const int Tp2 = (T + 2 < NT) ? T + 2 : NT - 1;
    const int Tp3 = (T + 3 < NT) ? T + 3 : NT - 1;
    // ph1: read buf0.kh0; stage (T+1).B1 -> buf1 (completes tile T+1)
    LDF(0, 0);
    STG(T + 1, 1, 1, 1);
    BAR(); LGKM0(); MFH(0); BAR();
    // ph2: stage (T+2).A0 -> buf0 (slot free since ph1 drained)
    STG(Tp2, 0, 0, 0);
    BAR(); MFH(1); BAR();
    // ph3: read buf0.kh1; stage (T+2).B0
    LDF(0, 1);
    STG(Tp2, 0, 1, 0);
    BAR(); LGKM0(); MFH(0); BAR();
    // ph4: stage (T+2).A1; WAIT vmcnt(6) -> tile T+1 all landed
    STG(Tp2, 1, 0, 0);
    VM6(); BAR(); MFH(1); BAR();
    // ph5: read buf1.kh0 (tile T+1); stage (T+2).B1
    LDF(1, 0);
    STG(Tp2, 1, 1, 0);
    BAR(); LGKM0(); MFH(0); BAR();
    // ph6: stage (T+3).A0 -> buf1
    STG(Tp3, 0, 0, 1);
    BAR(); MFH(1); BAR();
    // ph7: read buf1.kh1; stage (T+3).B0
    LDF(1, 1);
    STG(Tp3, 0, 1, 1);
    BAR(); LGKM0(); MFH(0); BAR();
    // ph8: stage (T+3).A1; WAIT vmcnt(6) -> tile T+2 all landed
    STG(Tp3, 1, 0, 1);
    VM6(); BAR(); MFH(1); BAR();
  }
  asm volatile("s_waitcnt vmcnt(0)" ::: "memory");
  BAR();

  // ---- epilogue: D row=(lane>>4)*4+j (M dim), col=lane&15 (N dim)
#pragma unroll
  for (int mi = 0; mi < 8; ++mi)
#pragma unroll
    for (int ni = 0; ni < 4; ++ni) {
      int row = m0 + wm * 128 + mi * 16 + lg * 4;
      int col = n0 + wn * 64 + ni * 16 + lr;
#pragma unroll
      for (int j = 0; j < 4; ++j)
        C[(size_t)(row + j) * N + col] = f2bf(acc[mi][ni][j]);
    }
#undef STG
#undef LDF
#undef MFH
#undef BAR
#undef LGKM0
#undef VM6
}

// ---------------------------------------------------------------- GEMM  C = A * B^T
// m97 structure (out-projection). T2 chunk swizzle as in gemm8_bt.
template <int OUT_BF16>
__global__ __launch_bounds__(256) void gemm_bt(const u16* __restrict__ A,
                                               const u16* __restrict__ B,
                                               void* __restrict__ Cv,
                                               int M, int N, int K) {
  __shared__ u16 lA[128 * 32];
  __shared__ u16 lB[128 * 32];
  const int t = threadIdx.x;
  const int m0 = blockIdx.y * 128, n0 = blockIdx.x * 128;
  const int w = t >> 6, l = t & 63, lr = l & 15, lg = l >> 4;
  const int wm = (w >> 1) * 64, wn = (w & 1) * 64;
  f32x4 acc[4][4] = {};
  const int srow = t >> 2;                          // staging row 0..63 (per round)
  const int scol = ((t & 3) ^ ((t >> 3) & 3)) * 8;  // inverse-swizzled source chunk
  const int swr = (lr >> 1) & 3;                    // read-side swizzle term
  const u16* Ag = A + (size_t)(m0 + srow) * K + scol;
  const u16* Bg = B + (size_t)(n0 + srow) * K + scol;

  for (int k0 = 0; k0 < K; k0 += 32) {
    __syncthreads();  // previous tile fully consumed
#pragma unroll
    for (int i = 0; i < 2; i++) {
      __builtin_amdgcn_global_load_lds((gas1)(Ag + (size_t)i * 64 * K + k0),
                                       (las3)(lA + (i * 256 + w * 64) * 8), 16, 0, 0);
      __builtin_amdgcn_global_load_lds((gas1)(Bg + (size_t)i * 64 * K + k0),
                                       (las3)(lB + (i * 256 + w * 64) * 8), 16, 0, 0);
    }
    __syncthreads();  // staged tile visible
    bf16x8 af[4], bfr[4];
#pragma unroll
    for (int mi = 0; mi < 4; mi++)
      af[mi] = *(const bf16x8*)&lA[(wm + mi * 16 + lr) * 32 + (lg ^ swr) * 8];
#pragma unroll
    for (int ni = 0; ni < 4; ni++)
      bfr[ni] = *(const bf16x8*)&lB[(wn + ni * 16 + lr) * 32 + (lg ^ swr) * 8];
#pragma unroll
    for (int mi = 0; mi < 4; mi++)
#pragma unroll
      for (int ni = 0; ni < 4; ni++)
        acc[mi][ni] =
            __builtin_amdgcn_mfma_f32_16x16x32_bf16(af[mi], bfr[ni], acc[mi][ni], 0, 0, 0);
  }

  // epilogue: D row=(lane>>4)*4+j, col=lane&15 (m89/m91-verified layout)
#pragma unroll
  for (int mi = 0; mi < 4; mi++)
#pragma unroll
    for (int ni = 0; ni < 4; ni++) {
      int row = m0 + wm + mi * 16 + lg * 4;
      int col = n0 + wn + ni * 16 + lr;
      if (OUT_BF16) {
        u16* C = (u16*)Cv;
#pragma unroll
        for (int j = 0; j < 4; j++) C[(size_t)(row + j) * N + col] = f2bf(acc[mi][ni][j]);
      } else {
        float* C = (float*)Cv;
#pragma unroll
        for (int j = 0; j < 4; j++) C[(size_t)(row + j) * N + col] = acc[mi][ni][j];
      }
    }
}

// ---------------------------------------------------------------- RoPE in place on q,k
// q additionally scaled by (1/sqrt(128)) * log2(e)  -> softmax runs in log2 domain.
__global__ void rope_apply(u16* __restrict__ qkv, const float* __restrict__ ct,
                           const float* __restrict__ st) {
  int i = blockIdx.x * blockDim.x + threadIdx.x;  // M_*32*64 threads
  int j = i & 63;
  int hh = (i >> 6) & 31;
  int row = i >> 11;
  int s = row & (S_ - 1);
  int col = (hh < 16) ? hh * 128 : 2048 + (hh - 16) * 128;
  u16* p = qkv + (size_t)row * NO_ + col + j;
  float e1 = bf2f(p[0]), e2 = bf2f(p[64]);
  float c = ct[(s << 6) + j], sn = st[(s << 6) + j];
  float o1 = e1 * c - e2 * sn;
  float o2 = e2 * c + e1 * sn;
  if (hh < 16) {  // fold softmax scale * log2(e) into q
    const float kq = 0.08838834764831845f * 1.4426950408889634f;
    o1 *= kq;
    o2 *= kq;
  }
  p[0] = f2bf(o1);
  p[64] = f2bf(o2);
}

// ---------------------------------------------------------------- V transpose
// qkv[b*S+s][4096 + h*128 + d] -> vt[(b*16+h)*128 + d][s]   (LDS-tiled, swizzled)
__global__ __launch_bounds__(256) void transpose_v(const u16* __restrict__ qkv,
                                                   u16* __restrict__ vt) {
  __shared__ u16 lds[128 * 64];
  const int bh = blockIdx.y;
  const int b = bh >> 4, h = bh & 15;
  const int s0 = blockIdx.x * 64;
  const int t = threadIdx.x;
  union { uint4 v; u16 e[8]; } uu;
#pragma unroll
  for (int i = 0; i < 4; i++) {
    int s = i * 16 + (t >> 4);
    int dc = (t & 15) * 8;
    uu.v = *(const uint4*)(qkv + (size_t)(b * S_ + s0 + s) * NO_ + 4096 + h * 128 + dc);
#pragma unroll
    for (int q = 0; q < 8; q++) {
      int d = dc + q;
      lds[d * 64 + (s ^ (((d >> 3) & 7) << 3))] = uu.e[q];
    }
  }
  __syncthreads();
#pragma unroll
  for (int i = 0; i < 4; i++) {
    int d = i * 32 + (t >> 3);
    int sc = (t & 7) * 8;
    uint4 v = *(const uint4*)&lds[d * 64 + (sc ^ (((d >> 3) & 7) << 3))];
    *(uint4*)(vt + (size_t)(bh * 128 + d) * S_ + s0 + sc) = v;
  }
}

// ---------------------------------------------------------------- flash attention
// grid (S/128, B*H); 256 thr = 4 waves; wave w owns q rows [q0+32w, q0+32w+32)
// as two 16-row groups g=0,1. Swapped QK^T, in-register log2 softmax, defer-max,
// double-buffered K/V staging, T5 setprio around MFMA clusters.
__global__ __launch_bounds__(256, 2) void flash_attn(const u16* __restrict__ qkv,
                                                     const u16* __restrict__ vt,
                                                     u16* __restrict__ ao) {
  __shared__ u16 lK[2][64 * 128];
  __shared__ u16 lV[2][128 * 64];
  __shared__ u16 lP[4][2][16 * 64];
  const int t = threadIdx.x;
  const int w = t >> 6, l = t & 63, lr = l & 15, lg = l >> 4;
  const int bh = blockIdx.y, b = bh >> 4, h = bh & 15;
  const int q0 = blockIdx.x * 128;

  // Q fragments (B operand now): lane holds Q[g*16+lr][c*32 + lg*8 + e]
  bf16x8 qf[2][4];
#pragma unroll
  for (int g = 0; g < 2; g++) {
    const u16* Qg = qkv + (size_t)(b * S_ + q0 + w * 32 + g * 16 + lr) * NO_ + h * 128;
#pragma unroll
    for (int c = 0; c < 4; c++) qf[g][c] = *(const bf16x8*)(Qg + c * 32 + lg * 8);
  }

  f32x4 acc[2][8] = {};
  float m_run[2] = {-INFINITY, -INFINITY};
  float l_run[2] = {0.f, 0.f};

  const u16* ksrc[4];
  const u16* vsrc[4];
#pragma unroll
  for (int q = 0; q < 4; q++) {
    int rt = w * 16 + q * 4 + (l >> 4);            // row within K tile
    int ck = (l & 15) ^ (rt & 15);                 // pre-swizzled source chunk
    ksrc[q] = qkv + (size_t)(b * S_ + rt) * NO_ + 2048 + h * 128 + ck * 8;
    int d = w * 32 + q * 8 + (l >> 3);             // row within V^T tile (d dim)
    int cv = (l & 7) ^ (d & 7);
    vsrc[q] = vt + (size_t)(bh * 128 + d) * S_ + cv * 8;
  }

  // ---- prologue: stage tile 0 into buffer 0
#pragma unroll
  for (int q = 0; q < 4; q++) {
    __builtin_amdgcn_global_load_lds((gas1)ksrc[q],
                                     (las3)(lK[0] + (w * 16 + q * 4) * 128), 16, 0, 0);
    __builtin_amdgcn_global_load_lds((gas1)vsrc[q],
                                     (las3)(lV[0] + (w * 32 + q * 8) * 64), 16, 0, 0);
    ksrc[q] += (size_t)64 * NO_;
    vsrc[q] += 64;
  }
  __syncthreads();  // buffer 0 staged

  const int NT = S_ / 64;
  for (int kt = 0; kt < NT; kt++) {
    const int cur = kt & 1;
    if (kt + 1 < NT) {
#pragma unroll
      for (int q = 0; q < 4; q++) {
        __builtin_amdgcn_global_load_lds((gas1)ksrc[q],
                                         (las3)(lK[cur ^ 1] + (w * 16 + q * 4) * 128), 16, 0, 0);
        __builtin_amdgcn_global_load_lds((gas1)vsrc[q],
                                         (las3)(lV[cur ^ 1] + (w * 32 + q * 8) * 64), 16, 0, 0);
        ksrc[q] += (size_t)64 * NO_;
        vsrc[q] += 64;
      }
    }

    // ---- S^T = K Q^T (log2 domain): lane (lr,lg) reg (cb,j) = S[cb*16+lg*4+j][g*16+lr]
    f32x4 sc[2][4];
#pragma unroll
    for (int g = 0; g < 2; g++)
#pragma unroll
      for (int cb = 0; cb < 4; cb++) sc[g][cb] = (f32x4){0.f, 0.f, 0.f, 0.f};
    __builtin_amdgcn_s_setprio(1);
#pragma unroll
    for (int cb = 0; cb < 4; cb++) {
      int r = cb * 16 + lr;
#pragma unroll
      for (int c = 0; c < 4; c++) {
        bf16x8 kf = *(const bf16x8*)&lK[cur][r * 128 + ((c * 32 + lg * 8) ^ ((r & 15) << 3))];
        sc[0][cb] = __builtin_amdgcn_mfma_f32_16x16x32_bf16(kf, qf[0][c], sc[0][cb], 0, 0, 0);
        sc[1][cb] = __builtin_amdgcn_mfma_f32_16x16x32_bf16(kf, qf[1][c], sc[1][cb], 0, 0, 0);
      }
    }
    __builtin_amdgcn_s_setprio(0);

    // ---- online softmax (log2 domain), in-register per q-row, defer-max
    float tmax[2];
#pragma unroll
    for (int g = 0; g < 2; g++) {
      float v = sc[g][0][0];
#pragma unroll
      for (int cb = 0; cb < 4; cb++)
#pragma unroll
        for (int j = 0; j < 4; j++) v = fmaxf(v, sc[g][cb][j]);
      v = fmaxf(v, __shfl_xor(v, 16));
      v = fmaxf(v, __shfl_xor(v, 32));
      tmax[g] = v;
    }
    bool ok = (tmax[0] <= m_run[0] + 10.0f) && (tmax[1] <= m_run[1] + 10.0f);
    if (!__all(ok)) {
      float resc[2];
#pragma unroll
      for (int g = 0; g < 2; g++) {
        float mn = fmaxf(m_run[g], tmax[g]);
        resc[g] = exp2f(m_run[g] - mn);
        m_run[g] = mn;
        l_run[g] *= resc[g];
      }
#pragma unroll
      for (int g = 0; g < 2; g++)
#pragma unroll
        for (int j = 0; j < 4; j++) {
          float rj = __shfl(resc[g], lg * 4 + j);  // lane lg*4+j has q-row lg*4+j
#pragma unroll
          for (int nb = 0; nb < 8; nb++) acc[g][nb][j] *= rj;
        }
    }
#pragma unroll
    for (int g = 0; g < 2; g++) {
      float ps = 0.f;
#pragma unroll
      for (int cb = 0; cb < 4; cb++)
#pragma unroll
        for (int j = 0; j < 4; j++) {
          float p = exp2f(sc[g][cb][j] - m_run[g]);
          sc[g][cb][j] = p;
          ps += p;
        }
      ps += __shfl_xor(ps, 16);
      ps += __shfl_xor(ps, 32);
      l_run[g] += ps;
    }

    // ---- P -> LDS: lane owns P[q=g*16+lr][k=cb*16+lg*4 .. +4] -> one b64 per (g,cb)
#pragma unroll
    for (int g = 0; g < 2; g++) {
      u16* lPw = lP[w][g];
#pragma unroll
      for (int cb = 0; cb < 4; cb++) {
        ushort4 pk;
        pk.x = f2bf(sc[g][cb][0]);
        pk.y = f2bf(sc[g][cb][1]);
        pk.z = f2bf(sc[g][cb][2]);
        pk.w = f2bf(sc[g][cb][3]);
        *(ushort4*)&lPw[lr * 64 + ((cb * 16 + lg * 4) ^ ((lr & 7) << 3))] = pk;
      }
    }

    // ---- O += P V : A = P[16][64] per group, B = V chunk (from V^T tile)
    __builtin_amdgcn_s_setprio(1);
#pragma unroll
    for (int c2 = 0; c2 < 2; c2++) {
      bf16x8 pf0 = *(const bf16x8*)&lP[w][0][lr * 64 + ((c2 * 32 + lg * 8) ^ ((lr & 7) << 3))];
      bf16x8 pf1 = *(const bf16x8*)&lP[w][1][lr * 64 + ((c2 * 32 + lg * 8) ^ ((lr & 7) << 3))];
#pragma unroll
      for (int nb = 0; nb < 8; nb++) {
        int r = nb * 16 + lr;
        bf16x8 vf = *(const bf16x8*)&lV[cur][r * 64 + ((c2 * 32 + lg * 8) ^ ((r & 7) << 3))];
        acc[0][nb] = __builtin_amdgcn_mfma_f32_16x16x32_bf16(pf0, vf, acc[0][nb], 0, 0, 0);
        acc[1][nb] = __builtin_amdgcn_mfma_f32_16x16x32_bf16(pf1, vf, acc[1][nb], 0, 0, 0);
      }
    }
    __builtin_amdgcn_s_setprio(0);

    __syncthreads();  // drains next-tile staging (covered by compute) + frees cur
  }

  // ---- epilogue: normalize and write attn_out[b*S+q][h*128+d] bf16
#pragma unroll
  for (int g = 0; g < 2; g++) {
    float linv[4];
#pragma unroll
    for (int j = 0; j < 4; j++) linv[j] = 1.0f / __shfl(l_run[g], lg * 4 + j);
#pragma unroll
    for (int nb = 0; nb < 8; nb++)
#pragma unroll
      for (int j = 0; j < 4; j++) {
        int qrow = q0 + w * 32 + g * 16 + lg * 4 + j;
        ao[(size_t)(b * S_ + qrow) * 2048 + h * 128 + nb * 16 + lr] =
            f2bf(acc[g][nb][j] * linv[j]);
      }
  }
}

// ---------------------------------------------------------------- launch
extern "C" void kernel_launch(void* const* d_in, const int* in_sizes, int n_in,
                              void* d_out, int out_size, void* d_ws, size_t ws_size,
                              hipStream_t stream) {
  const float* x = (const float*)d_in[0];
  const float* wqkv = (const float*)d_in[1];
  const float* wout = (const float*)d_in[2];
  float* out = (float*)d_out;

  char* ws = (char*)d_ws;
  u16* xbf = (u16*)(ws);                              // 16 MiB (reused as attn_out)
  u16* wqkvb = (u16*)(ws + ((size_t)16 << 20));       // 24 MiB
  u16* woutb = (u16*)(ws + ((size_t)40 << 20));       // 8 MiB
  u16* qkv = (u16*)(ws + ((size_t)48 << 20));         // 48 MiB
  u16* vtb = (u16*)(ws + ((size_t)96 << 20));         // 16 MiB
  float* ct = (float*)(ws + ((size_t)112 << 20));     // 0.5 MiB
  float* st = (float*)(ws + ((size_t)112 << 20) + ((size_t)1 << 19));
  u16* aout = xbf;  // x_bf16 dead after gemm_qkv

  cvt_bf16<<<4096, 256, 0, stream>>>(x, xbf, M_ * DM_);
  cvt_bf16<<<4096, 256, 0, stream>>>(wqkv, wqkvb, NO_ * DM_);
  cvt_bf16<<<4096, 256, 0, stream>>>(wout, woutb, DM_ * DM_);
  rope_tables<<<(S_ * 64) / 256, 256, 0, stream>>>(ct, st);
  gemm8_bt<<<dim3(NO_ / 256, M_ / 256), 512, 0, stream>>>(xbf, wqkvb, qkv, M_, NO_, DM_);
  rope_apply<<<(M_ * 32 * 64) / 256, 256, 0, stream>>>(qkv, ct, st);
  transpose_v<<<dim3(S_ / 64, B_ * H_), 256, 0, stream>>>(qkv, vtb);
  flash_attn<<<dim3(S_ / 128, B_ * H_), 256, 0, stream>>>(qkv, vtb, aout);
  gemm_bt<0><<<dim3(DM_ / 128, M_ / 128), 256, 0, stream>>>(aout, woutb, out, M_, DM_, DM_);
}